// Round 2
// baseline (2664.400 us; speedup 1.0000x reference)
//
#include <hip/hip_runtime.h>
#include <hip/hip_bf16.h>

#define N_NODES   100000
#define N_TYPE_A  50000
#define N_EDGES   600000
#define D_IN      256
#define DD        128
#define LN_EPS    1e-5f

typedef short bf16x8 __attribute__((ext_vector_type(8)));
typedef float f32x4  __attribute__((ext_vector_type(4)));

__device__ __forceinline__ float bf2f(unsigned short u) {
  unsigned v = ((unsigned)u) << 16;
  return __builtin_bit_cast(float, v);
}
__device__ __forceinline__ short f2bf(float f) {
  unsigned u = __builtin_bit_cast(unsigned, f);
  u += 0x7FFFu + ((u >> 16) & 1u);
  return (short)(u >> 16);
}

// ---------------- Encoder: x[0:50000] = x_typeA @ W_mlp.T + b_mlp (bf16 out) ----------------
__global__ __launch_bounds__(256) void enc_gemm(const float* __restrict__ A,
                                                const float* __restrict__ W,
                                                const float* __restrict__ bias,
                                                unsigned short* __restrict__ xout) {
  int wave = threadIdx.x >> 6, lane = threadIdx.x & 63;
  int l15 = lane & 15, lhi = lane >> 4;
  int r0 = blockIdx.x * 64 + wave * 16;
  f32x4 acc[8];
#pragma unroll
  for (int i = 0; i < 8; ++i) acc[i] = (f32x4){0.f, 0.f, 0.f, 0.f};
  int rowA = r0 + l15; if (rowA >= N_TYPE_A) rowA = N_TYPE_A - 1;
#pragma unroll
  for (int kk = 0; kk < 8; ++kk) {
    int kbase = kk * 32 + lhi * 8;
    const float* ap = A + (size_t)rowA * D_IN + kbase;
    float4 a0 = *(const float4*)ap; float4 a1 = *(const float4*)(ap + 4);
    bf16x8 af;
    af[0]=f2bf(a0.x); af[1]=f2bf(a0.y); af[2]=f2bf(a0.z); af[3]=f2bf(a0.w);
    af[4]=f2bf(a1.x); af[5]=f2bf(a1.y); af[6]=f2bf(a1.z); af[7]=f2bf(a1.w);
#pragma unroll
    for (int nt = 0; nt < 8; ++nt) {
      const float* bp = W + (size_t)(nt * 16 + l15) * D_IN + kbase;
      float4 b0 = *(const float4*)bp; float4 b1 = *(const float4*)(bp + 4);
      bf16x8 bfr;
      bfr[0]=f2bf(b0.x); bfr[1]=f2bf(b0.y); bfr[2]=f2bf(b0.z); bfr[3]=f2bf(b0.w);
      bfr[4]=f2bf(b1.x); bfr[5]=f2bf(b1.y); bfr[6]=f2bf(b1.z); bfr[7]=f2bf(b1.w);
      acc[nt] = __builtin_amdgcn_mfma_f32_16x16x32_bf16(af, bfr, acc[nt], 0, 0, 0);
    }
  }
#pragma unroll
  for (int nt = 0; nt < 8; ++nt) {
    int col = nt * 16 + l15;
    float bv = bias[col];
#pragma unroll
    for (int r = 0; r < 4; ++r) {
      int row = r0 + lhi * 4 + r;
      if (row < N_TYPE_A) xout[(size_t)row * DD + col] = (unsigned short)f2bf(acc[nt][r] + bv);
    }
  }
}

// ---------------- emb_B f32 -> bf16 copy into x[50000:] ----------------
__global__ __launch_bounds__(256) void embB_copy(const float* __restrict__ e,
                                                 unsigned short* __restrict__ xout) {
  size_t i = ((size_t)blockIdx.x * 256 + threadIdx.x) * 4;
  float4 v = *(const float4*)(e + i);
  unsigned short* o = xout + i;
  o[0] = (unsigned short)f2bf(v.x); o[1] = (unsigned short)f2bf(v.y);
  o[2] = (unsigned short)f2bf(v.z); o[3] = (unsigned short)f2bf(v.w);
}

// ---------------- degree count + inverse sqrt ----------------
__global__ __launch_bounds__(256) void deg_count(const int* __restrict__ es,
                                                 const int* __restrict__ et,
                                                 int* degS, int* degT) {
  int e = blockIdx.x * 256 + threadIdx.x;
  if (e < N_EDGES) { atomicAdd(&degS[es[e]], 1); atomicAdd(&degT[et[e]], 1); }
}

__global__ __launch_bounds__(256) void inv_kernel(const int* __restrict__ degS,
                                                  const int* __restrict__ degT,
                                                  float* __restrict__ invS,
                                                  float* __restrict__ invT) {
  int n = blockIdx.x * 256 + threadIdx.x;
  if (n < N_NODES) {
    int d = degS[n]; invS[n] = d > 0 ? rsqrtf((float)d) : 0.f;
    int e = degT[n]; invT[n] = e > 0 ? rsqrtf((float)e) : 0.f;
  }
}

// ---- edge phase: scatter composed features (pre-transform), both inv factors folded ----
__global__ __launch_bounds__(256) void edge_kernel(const unsigned short* __restrict__ x,
                                                   const float* __restrict__ rel,
                                                   const int* __restrict__ es,
                                                   const int* __restrict__ er,
                                                   const int* __restrict__ et,
                                                   const float* __restrict__ invS,
                                                   const float* __restrict__ invT,
                                                   float* accO, float* accI) {
  int e = blockIdx.x * 4 + (threadIdx.x >> 6);
  int lane = threadIdx.x & 63;
  int s = es[e], r = er[e], t = et[e];
  float f = invS[s] * invT[t];
  int d = lane * 2;
  ushort2 xa = *(const ushort2*)(x + (size_t)s * DD + d);
  ushort2 xb = *(const ushort2*)(x + (size_t)t * DD + d);
  float2 re = *(const float2*)(rel + (size_t)r * DD + d);
  float xs0 = bf2f(xa.x), xs1 = bf2f(xa.y);
  float xt0 = bf2f(xb.x), xt1 = bf2f(xb.y);
  float* po = accO + (size_t)t * DD + d;
  float* pi = accI + (size_t)s * DD + d;
  unsafeAtomicAdd(po,     (xs0 - re.x) * f);
  unsafeAtomicAdd(po + 1, (xs1 - re.y) * f);
  unsafeAtomicAdd(pi,     (xt0 - re.x) * f);
  unsafeAtomicAdd(pi + 1, (xt1 - re.y) * f);
}

// ---------------- per-layer node transform: 3 GEMMs fused, K=3*128 ----------------
__global__ __launch_bounds__(256) void conv_gemm(const float* accO, const float* accI,
                                                 const unsigned short* __restrict__ x,
                                                 const float* __restrict__ wOut,
                                                 const float* __restrict__ wIn,
                                                 const float* __restrict__ wLoop,
                                                 const float* __restrict__ loopRel,
                                                 const float* __restrict__ bias,
                                                 float* pre) {
  int wave = threadIdx.x >> 6, lane = threadIdx.x & 63;
  int l15 = lane & 15, lhi = lane >> 4;
  int r0 = blockIdx.x * 64 + wave * 16;
  f32x4 acc[8];
#pragma unroll
  for (int i = 0; i < 8; ++i) acc[i] = (f32x4){0.f, 0.f, 0.f, 0.f};
  int rowA = r0 + l15; if (rowA >= N_NODES) rowA = N_NODES - 1;
#pragma unroll
  for (int m = 0; m < 3; ++m) {
    const float* wmat = (m == 0) ? wOut : ((m == 1) ? wIn : wLoop);
#pragma unroll
    for (int kk = 0; kk < 4; ++kk) {
      int kbase = kk * 32 + lhi * 8;
      bf16x8 af;
      if (m == 0) {
        const float* ap = accO + (size_t)rowA * DD + kbase;
        float4 a0 = *(const float4*)ap; float4 a1 = *(const float4*)(ap + 4);
        af[0]=f2bf(a0.x); af[1]=f2bf(a0.y); af[2]=f2bf(a0.z); af[3]=f2bf(a0.w);
        af[4]=f2bf(a1.x); af[5]=f2bf(a1.y); af[6]=f2bf(a1.z); af[7]=f2bf(a1.w);
      } else if (m == 1) {
        const float* ap = accI + (size_t)rowA * DD + kbase;
        float4 a0 = *(const float4*)ap; float4 a1 = *(const float4*)(ap + 4);
        af[0]=f2bf(a0.x); af[1]=f2bf(a0.y); af[2]=f2bf(a0.z); af[3]=f2bf(a0.w);
        af[4]=f2bf(a1.x); af[5]=f2bf(a1.y); af[6]=f2bf(a1.z); af[7]=f2bf(a1.w);
      } else {
        const unsigned short* xp = x + (size_t)rowA * DD + kbase;
        float4 l0 = *(const float4*)(loopRel + kbase);
        float4 l1 = *(const float4*)(loopRel + kbase + 4);
        af[0]=f2bf(bf2f(xp[0])-l0.x); af[1]=f2bf(bf2f(xp[1])-l0.y);
        af[2]=f2bf(bf2f(xp[2])-l0.z); af[3]=f2bf(bf2f(xp[3])-l0.w);
        af[4]=f2bf(bf2f(xp[4])-l1.x); af[5]=f2bf(bf2f(xp[5])-l1.y);
        af[6]=f2bf(bf2f(xp[6])-l1.z); af[7]=f2bf(bf2f(xp[7])-l1.w);
      }
#pragma unroll
      for (int nt = 0; nt < 8; ++nt) {
        const float* bp = wmat + (size_t)(nt * 16 + l15) * DD + kbase;
        float4 b0 = *(const float4*)bp; float4 b1 = *(const float4*)(bp + 4);
        bf16x8 bfr;
        bfr[0]=f2bf(b0.x); bfr[1]=f2bf(b0.y); bfr[2]=f2bf(b0.z); bfr[3]=f2bf(b0.w);
        bfr[4]=f2bf(b1.x); bfr[5]=f2bf(b1.y); bfr[6]=f2bf(b1.z); bfr[7]=f2bf(b1.w);
        acc[nt] = __builtin_amdgcn_mfma_f32_16x16x32_bf16(af, bfr, acc[nt], 0, 0, 0);
      }
    }
  }
  const float third = 1.0f / 3.0f;
#pragma unroll
  for (int nt = 0; nt < 8; ++nt) {
    int col = nt * 16 + l15;
    float bv = bias[col];
#pragma unroll
    for (int r = 0; r < 4; ++r) {
      int row = r0 + lhi * 4 + r;
      if (row < N_NODES) pre[(size_t)row * DD + col] = acc[nt][r] * third + bv;
    }
  }
}

// ---------------- LayerNorm (optional relu first); writes bf16 or f32 ----------------
__global__ __launch_bounds__(256) void ln_kernel(const float* __restrict__ pre,
                                                 const float* __restrict__ g,
                                                 const float* __restrict__ b,
                                                 unsigned short* out_bf, float* out_f,
                                                 int do_relu) {
  int wave = threadIdx.x >> 6, lane = threadIdx.x & 63;
  int row = blockIdx.x * 4 + wave;
  int d = lane * 2;
  float2 v = *(const float2*)(pre + (size_t)row * DD + d);
  if (do_relu) { v.x = fmaxf(v.x, 0.f); v.y = fmaxf(v.y, 0.f); }
  float s = v.x + v.y, ss = v.x * v.x + v.y * v.y;
#pragma unroll
  for (int off = 1; off < 64; off <<= 1) {
    s += __shfl_xor(s, off);
    ss += __shfl_xor(ss, off);
  }
  float mu = s * (1.f / 128.f);
  float var = ss * (1.f / 128.f) - mu * mu;
  float rstd = rsqrtf(var + LN_EPS);
  float y0 = (v.x - mu) * rstd * g[d] + b[d];
  float y1 = (v.y - mu) * rstd * g[d + 1] + b[d + 1];
  if (out_bf) {
    out_bf[(size_t)row * DD + d]     = (unsigned short)f2bf(y0);
    out_bf[(size_t)row * DD + d + 1] = (unsigned short)f2bf(y1);
  } else {
    out_f[(size_t)row * DD + d]     = y0;
    out_f[(size_t)row * DD + d + 1] = y1;
  }
}

extern "C" void kernel_launch(void* const* d_in, const int* in_sizes, int n_in,
                              void* d_out, int out_size, void* d_ws, size_t ws_size,
                              hipStream_t stream) {
  const float* x_typeA  = (const float*)d_in[0];
  const float* W_mlp    = (const float*)d_in[1];
  const float* b_mlp    = (const float*)d_in[2];
  const float* emb_B    = (const float*)d_in[3];
  const float* rel_emb0 = (const float*)d_in[4];
  const float* loop_rel0= (const float*)d_in[5];
  const float* w_loop0  = (const float*)d_in[6];
  const float* w_in0    = (const float*)d_in[7];
  const float* w_out0   = (const float*)d_in[8];
  const float* bias0    = (const float*)d_in[9];
  const float* ln_g0    = (const float*)d_in[10];
  const float* ln_b0    = (const float*)d_in[11];
  const float* rel_emb1 = (const float*)d_in[12];
  const float* loop_rel1= (const float*)d_in[13];
  const float* w_loop1  = (const float*)d_in[14];
  const float* w_in1    = (const float*)d_in[15];
  const float* w_out1   = (const float*)d_in[16];
  const float* bias1    = (const float*)d_in[17];
  const float* ln_g1    = (const float*)d_in[18];
  const float* ln_b1    = (const float*)d_in[19];
  const int* edge_src   = (const int*)d_in[20];
  const int* edge_rel   = (const int*)d_in[21];
  const int* edge_dst   = (const int*)d_in[22];

  // ---- workspace layout: high-water mark 77,600,000 B (was 129.6 MB — OOB suspect) ----
  char* ws = (char*)d_ws;
  unsigned short* xbf = (unsigned short*)ws;            // [0, 25.6M)
  float* invS = (float*)(ws + 25600000);                // [25.6M, 26.0M)
  float* invT = (float*)(ws + 26000000);                // [26.0M, 26.4M)
  float* accI = (float*)(ws + 26400000);                // [26.4M, 77.6M)
  int*   degS = (int*)(ws + 26400000);                  // overlaps accI head (pre-loop only)
  int*   degT = (int*)(ws + 26800000);
  float* accO = (float*)d_out;                          // d_out doubles as accO / pre / result
  float* out  = (float*)d_out;

  // encoder + type-B embedding -> unified bf16 node table
  enc_gemm<<<(N_TYPE_A + 63) / 64, 256, 0, stream>>>(x_typeA, W_mlp, b_mlp, xbf);
  embB_copy<<<6250, 256, 0, stream>>>(emb_B, xbf + (size_t)N_TYPE_A * DD);

  // degrees (edge lists are layer-invariant)
  hipMemsetAsync(degS, 0, 2 * N_NODES * sizeof(int), stream);
  deg_count<<<(N_EDGES + 255) / 256, 256, 0, stream>>>(edge_src, edge_dst, degS, degT);
  inv_kernel<<<(N_NODES + 255) / 256, 256, 0, stream>>>(degS, degT, invS, invT);

  for (int layer = 0; layer < 2; ++layer) {
    hipMemsetAsync(accO, 0, (size_t)N_NODES * DD * sizeof(float), stream);
    hipMemsetAsync(accI, 0, (size_t)N_NODES * DD * sizeof(float), stream);
    edge_kernel<<<N_EDGES / 4, 256, 0, stream>>>(
        xbf, layer ? rel_emb1 : rel_emb0, edge_src, edge_rel, edge_dst,
        invS, invT, accO, accI);
    conv_gemm<<<(N_NODES + 63) / 64, 256, 0, stream>>>(
        accO, accI, xbf,
        layer ? w_out1 : w_out0, layer ? w_in1 : w_in0, layer ? w_loop1 : w_loop0,
        layer ? loop_rel1 : loop_rel0, layer ? bias1 : bias0, accO);
    ln_kernel<<<N_NODES / 4, 256, 0, stream>>>(
        accO, layer ? ln_g1 : ln_g0, layer ? ln_b1 : ln_b0,
        layer ? nullptr : xbf, layer ? out : nullptr, layer ? 0 : 1);
  }
}

// Round 4
// 936.171 us; speedup vs baseline: 2.8461x; 2.8461x over previous
//
#include <hip/hip_runtime.h>
#include <hip/hip_bf16.h>

#define N_NODES   100000
#define N_TYPE_A  50000
#define N_EDGES   600000
#define D_IN      256
#define DD        128
#define LN_EPS    1e-5f
#define SCAN_NBLK 391   // ceil(N_NODES/256)

typedef short bf16x8 __attribute__((ext_vector_type(8)));
typedef float f32x4  __attribute__((ext_vector_type(4)));

__device__ __forceinline__ float bf2f(unsigned short u) {
  unsigned v = ((unsigned)u) << 16;
  return __builtin_bit_cast(float, v);
}
__device__ __forceinline__ unsigned short f2bf(float f) {
  unsigned u = __builtin_bit_cast(unsigned, f);
  u += 0x7FFFu + ((u >> 16) & 1u);
  return (unsigned short)(u >> 16);
}

// ---------------- Encoder: x[0:50000] = x_typeA @ W_mlp.T + b_mlp (bf16 out) ----------------
__global__ __launch_bounds__(256) void enc_gemm(const float* __restrict__ A,
                                                const float* __restrict__ W,
                                                const float* __restrict__ bias,
                                                unsigned short* __restrict__ xout) {
  int wave = threadIdx.x >> 6, lane = threadIdx.x & 63;
  int l15 = lane & 15, lhi = lane >> 4;
  int r0 = blockIdx.x * 64 + wave * 16;
  f32x4 acc[8];
#pragma unroll
  for (int i = 0; i < 8; ++i) acc[i] = (f32x4){0.f, 0.f, 0.f, 0.f};
  int rowA = r0 + l15; if (rowA >= N_TYPE_A) rowA = N_TYPE_A - 1;
#pragma unroll
  for (int kk = 0; kk < 8; ++kk) {
    int kbase = kk * 32 + lhi * 8;
    const float* ap = A + (size_t)rowA * D_IN + kbase;
    float4 a0 = *(const float4*)ap; float4 a1 = *(const float4*)(ap + 4);
    bf16x8 af;
    af[0]=f2bf(a0.x); af[1]=f2bf(a0.y); af[2]=f2bf(a0.z); af[3]=f2bf(a0.w);
    af[4]=f2bf(a1.x); af[5]=f2bf(a1.y); af[6]=f2bf(a1.z); af[7]=f2bf(a1.w);
#pragma unroll
    for (int nt = 0; nt < 8; ++nt) {
      const float* bp = W + (size_t)(nt * 16 + l15) * D_IN + kbase;
      float4 b0 = *(const float4*)bp; float4 b1 = *(const float4*)(bp + 4);
      bf16x8 bfr;
      bfr[0]=f2bf(b0.x); bfr[1]=f2bf(b0.y); bfr[2]=f2bf(b0.z); bfr[3]=f2bf(b0.w);
      bfr[4]=f2bf(b1.x); bfr[5]=f2bf(b1.y); bfr[6]=f2bf(b1.z); bfr[7]=f2bf(b1.w);
      acc[nt] = __builtin_amdgcn_mfma_f32_16x16x32_bf16(af, bfr, acc[nt], 0, 0, 0);
    }
  }
#pragma unroll
  for (int nt = 0; nt < 8; ++nt) {
    int col = nt * 16 + l15;
    float bv = bias[col];
#pragma unroll
    for (int r = 0; r < 4; ++r) {
      int row = r0 + lhi * 4 + r;
      if (row < N_TYPE_A) xout[(size_t)row * DD + col] = f2bf(acc[nt][r] + bv);
    }
  }
}

// ---------------- emb_B f32 -> bf16 copy into x[50000:] ----------------
__global__ __launch_bounds__(256) void embB_copy(const float* __restrict__ e,
                                                 unsigned short* __restrict__ xout) {
  size_t i = ((size_t)blockIdx.x * 256 + threadIdx.x) * 4;
  float4 v = *(const float4*)(e + i);
  unsigned short* o = xout + i;
  o[0] = f2bf(v.x); o[1] = f2bf(v.y); o[2] = f2bf(v.z); o[3] = f2bf(v.w);
}

// ---------------- degree count ----------------
__global__ __launch_bounds__(256) void deg_count(const int* __restrict__ es,
                                                 const int* __restrict__ et,
                                                 int* cntS, int* cntT) {
  int e = blockIdx.x * 256 + threadIdx.x;
  if (e < N_EDGES) { atomicAdd(&cntS[es[e]], 1); atomicAdd(&cntT[et[e]], 1); }
}

__global__ __launch_bounds__(256) void inv_kernel(const int* __restrict__ cntS,
                                                  const int* __restrict__ cntT,
                                                  float* __restrict__ invS,
                                                  float* __restrict__ invT) {
  int n = blockIdx.x * 256 + threadIdx.x;
  if (n < N_NODES) {
    int d = cntS[n]; invS[n] = d > 0 ? rsqrtf((float)d) : 0.f;
    int e = cntT[n]; invT[n] = e > 0 ? rsqrtf((float)e) : 0.f;
  }
}

// ---------------- exclusive scan (3 kernels) ----------------
__global__ __launch_bounds__(256) void scan1(const int* __restrict__ cnt,
                                             int* __restrict__ rowptr,
                                             int* __restrict__ bsums) {
  __shared__ int tmp[256];
  int gid = blockIdx.x * 256 + threadIdx.x;
  int v = (gid < N_NODES) ? cnt[gid] : 0;
  tmp[threadIdx.x] = v; __syncthreads();
#pragma unroll
  for (int off = 1; off < 256; off <<= 1) {
    int t = (threadIdx.x >= off) ? tmp[threadIdx.x - off] : 0;
    __syncthreads();
    tmp[threadIdx.x] += t;
    __syncthreads();
  }
  if (gid < N_NODES) rowptr[gid] = tmp[threadIdx.x] - v;  // exclusive within block
  if (threadIdx.x == 255) bsums[blockIdx.x] = tmp[255];
}

__global__ __launch_bounds__(512) void scan2(int* __restrict__ bsums) {
  __shared__ int tmp[512];
  int v = (threadIdx.x < SCAN_NBLK) ? bsums[threadIdx.x] : 0;
  tmp[threadIdx.x] = v; __syncthreads();
#pragma unroll
  for (int off = 1; off < 512; off <<= 1) {
    int t = (threadIdx.x >= off) ? tmp[threadIdx.x - off] : 0;
    __syncthreads();
    tmp[threadIdx.x] += t;
    __syncthreads();
  }
  if (threadIdx.x < SCAN_NBLK) bsums[threadIdx.x] = tmp[threadIdx.x] - v;  // exclusive block offsets
}

__global__ __launch_bounds__(256) void scan3(int* __restrict__ rowptr,
                                             const int* __restrict__ bsums) {
  int gid = blockIdx.x * 256 + threadIdx.x;
  if (gid < N_NODES) rowptr[gid] += bsums[blockIdx.x];
  if (gid == 0) rowptr[N_NODES] = N_EDGES;
}

// ---------------- CSR fill: payload = {idx | rel<<17, f32 factor} ----------------
__global__ __launch_bounds__(256) void fill_kernel(const int* __restrict__ es,
                                                   const int* __restrict__ er,
                                                   const int* __restrict__ et,
                                                   const float* __restrict__ invS,
                                                   const float* __restrict__ invT,
                                                   const int* __restrict__ rowptrT,
                                                   const int* __restrict__ rowptrS,
                                                   int* cntT, int* cntS,
                                                   uint2* __restrict__ payT,
                                                   uint2* __restrict__ payS) {
  int e = blockIdx.x * 256 + threadIdx.x;
  if (e >= N_EDGES) return;
  int s = es[e], r = er[e], t = et[e];
  unsigned fb = __builtin_bit_cast(unsigned, invS[s] * invT[t]);
  int pT = rowptrT[t] + atomicAdd(&cntT[t], 1);
  payT[pT] = make_uint2((unsigned)s | ((unsigned)r << 17), fb);
  int pS = rowptrS[s] + atomicAdd(&cntS[s], 1);
  payS[pS] = make_uint2((unsigned)t | ((unsigned)r << 17), fb);
}

// ---------------- gather aggregation: one wave per node, no atomics ----------------
__global__ __launch_bounds__(256) void agg_kernel(const unsigned short* __restrict__ x,
                                                  const float* __restrict__ rel,
                                                  const int* __restrict__ rowptrT,
                                                  const uint2* __restrict__ payT,
                                                  const int* __restrict__ rowptrS,
                                                  const uint2* __restrict__ payS,
                                                  float* __restrict__ accO,
                                                  unsigned short* __restrict__ accIbf) {
  int wave = threadIdx.x >> 6, lane = threadIdx.x & 63;
  int n = blockIdx.x * 4 + wave;
  int d = lane * 2;
  // out-direction: edges into n (dst-CSR) -> accO[n]
  float a0 = 0.f, a1 = 0.f;
  int b0 = rowptrT[n], b1 = rowptrT[n + 1];
  for (int i = b0; i < b1; ++i) {
    uint2 p = payT[i];
    int idx = p.x & 131071; int r = p.x >> 17;
    float f = __builtin_bit_cast(float, p.y);
    ushort2 xs = *(const ushort2*)(x + (size_t)idx * DD + d);
    float2 re = *(const float2*)(rel + (size_t)r * DD + d);
    a0 += (bf2f(xs.x) - re.x) * f;
    a1 += (bf2f(xs.y) - re.y) * f;
  }
  accO[(size_t)n * DD + d]     = a0;
  accO[(size_t)n * DD + d + 1] = a1;
  // in-direction: edges out of n (src-CSR) -> accIbf[n]
  a0 = 0.f; a1 = 0.f;
  b0 = rowptrS[n]; b1 = rowptrS[n + 1];
  for (int i = b0; i < b1; ++i) {
    uint2 p = payS[i];
    int idx = p.x & 131071; int r = p.x >> 17;
    float f = __builtin_bit_cast(float, p.y);
    ushort2 xs = *(const ushort2*)(x + (size_t)idx * DD + d);
    float2 re = *(const float2*)(rel + (size_t)r * DD + d);
    a0 += (bf2f(xs.x) - re.x) * f;
    a1 += (bf2f(xs.y) - re.y) * f;
  }
  *(ushort2*)(accIbf + (size_t)n * DD + d) = make_ushort2(f2bf(a0), f2bf(a1));
}

// ------- per-layer transform: 3 fused GEMMs (K=384) + /3 + bias + [relu] + LayerNorm -------
// NOTE: `x` must NOT be __restrict__ — in layer 0 it aliases outbf (in-place x update).
// Per-wave ordering (reads of own rows precede writes of own rows) makes the alias safe,
// but only without restrict's reordering license.
template<bool RELU, bool OUTBF>
__global__ __launch_bounds__(256) void conv_ln(const float* accO,
                                               const unsigned short* accIbf,
                                               const unsigned short* x,
                                               const float* __restrict__ wOut,
                                               const float* __restrict__ wIn,
                                               const float* __restrict__ wLoop,
                                               const float* __restrict__ loopRel,
                                               const float* __restrict__ bias,
                                               const float* __restrict__ g,
                                               const float* __restrict__ bln,
                                               unsigned short* outbf, float* outf) {
  int wave = threadIdx.x >> 6, lane = threadIdx.x & 63;
  int l15 = lane & 15, lhi = lane >> 4;
  int r0 = blockIdx.x * 64 + wave * 16;
  f32x4 acc[8];
#pragma unroll
  for (int i = 0; i < 8; ++i) acc[i] = (f32x4){0.f, 0.f, 0.f, 0.f};
  int rowA = r0 + l15; if (rowA >= N_NODES) rowA = N_NODES - 1;
#pragma unroll
  for (int m = 0; m < 3; ++m) {
    const float* wmat = (m == 0) ? wOut : ((m == 1) ? wIn : wLoop);
#pragma unroll
    for (int kk = 0; kk < 4; ++kk) {
      int kbase = kk * 32 + lhi * 8;
      bf16x8 af;
      if (m == 0) {
        const float* ap = accO + (size_t)rowA * DD + kbase;
        float4 a0 = *(const float4*)ap; float4 a1 = *(const float4*)(ap + 4);
        af[0]=f2bf(a0.x); af[1]=f2bf(a0.y); af[2]=f2bf(a0.z); af[3]=f2bf(a0.w);
        af[4]=f2bf(a1.x); af[5]=f2bf(a1.y); af[6]=f2bf(a1.z); af[7]=f2bf(a1.w);
      } else if (m == 1) {
        af = *(const bf16x8*)(accIbf + (size_t)rowA * DD + kbase);  // direct bf16 load
      } else {
        const unsigned short* xp = x + (size_t)rowA * DD + kbase;
        float4 l0 = *(const float4*)(loopRel + kbase);
        float4 l1 = *(const float4*)(loopRel + kbase + 4);
        af[0]=f2bf(bf2f(xp[0])-l0.x); af[1]=f2bf(bf2f(xp[1])-l0.y);
        af[2]=f2bf(bf2f(xp[2])-l0.z); af[3]=f2bf(bf2f(xp[3])-l0.w);
        af[4]=f2bf(bf2f(xp[4])-l1.x); af[5]=f2bf(bf2f(xp[5])-l1.y);
        af[6]=f2bf(bf2f(xp[6])-l1.z); af[7]=f2bf(bf2f(xp[7])-l1.w);
      }
#pragma unroll
      for (int nt = 0; nt < 8; ++nt) {
        const float* bp = wmat + (size_t)(nt * 16 + l15) * DD + kbase;
        float4 b0 = *(const float4*)bp; float4 b1 = *(const float4*)(bp + 4);
        bf16x8 bfr;
        bfr[0]=f2bf(b0.x); bfr[1]=f2bf(b0.y); bfr[2]=f2bf(b0.z); bfr[3]=f2bf(b0.w);
        bfr[4]=f2bf(b1.x); bfr[5]=f2bf(b1.y); bfr[6]=f2bf(b1.z); bfr[7]=f2bf(b1.w);
        acc[nt] = __builtin_amdgcn_mfma_f32_16x16x32_bf16(af, bfr, acc[nt], 0, 0, 0);
      }
    }
  }
  // epilogue: v = acc/3 + bias ; [relu] ; LayerNorm over each row (128 cols)
  // C layout: col = nt*16 + l15, row = r0 + lhi*4 + r -> 16 lanes (same lhi) hold one row
  float bv[8], gv[8], bb[8];
#pragma unroll
  for (int nt = 0; nt < 8; ++nt) {
    int col = nt * 16 + l15;
    bv[nt] = bias[col]; gv[nt] = g[col]; bb[nt] = bln[col];
  }
  const float third = 1.0f / 3.0f;
  float s0[4] = {0.f, 0.f, 0.f, 0.f}, s1[4] = {0.f, 0.f, 0.f, 0.f};
#pragma unroll
  for (int nt = 0; nt < 8; ++nt)
#pragma unroll
    for (int r = 0; r < 4; ++r) {
      float v = acc[nt][r] * third + bv[nt];
      if (RELU) v = fmaxf(v, 0.f);
      acc[nt][r] = v;
      s0[r] += v; s1[r] += v * v;
    }
#pragma unroll
  for (int off = 1; off < 16; off <<= 1)
#pragma unroll
    for (int r = 0; r < 4; ++r) {
      s0[r] += __shfl_xor(s0[r], off);
      s1[r] += __shfl_xor(s1[r], off);
    }
  float mu[4], rstd[4];
#pragma unroll
  for (int r = 0; r < 4; ++r) {
    mu[r] = s0[r] * (1.f / 128.f);
    float var = s1[r] * (1.f / 128.f) - mu[r] * mu[r];
    rstd[r] = rsqrtf(var + LN_EPS);
  }
#pragma unroll
  for (int nt = 0; nt < 8; ++nt) {
    int col = nt * 16 + l15;
#pragma unroll
    for (int r = 0; r < 4; ++r) {
      int row = r0 + lhi * 4 + r;
      if (row < N_NODES) {
        float y = (acc[nt][r] - mu[r]) * rstd[r] * gv[nt] + bb[nt];
        if (OUTBF) outbf[(size_t)row * DD + col] = f2bf(y);
        else       outf[(size_t)row * DD + col]  = y;
      }
    }
  }
}

extern "C" void kernel_launch(void* const* d_in, const int* in_sizes, int n_in,
                              void* d_out, int out_size, void* d_ws, size_t ws_size,
                              hipStream_t stream) {
  const float* x_typeA  = (const float*)d_in[0];
  const float* W_mlp    = (const float*)d_in[1];
  const float* b_mlp    = (const float*)d_in[2];
  const float* emb_B    = (const float*)d_in[3];
  const float* rel_emb0 = (const float*)d_in[4];
  const float* loop_rel0= (const float*)d_in[5];
  const float* w_loop0  = (const float*)d_in[6];
  const float* w_in0    = (const float*)d_in[7];
  const float* w_out0   = (const float*)d_in[8];
  const float* bias0    = (const float*)d_in[9];
  const float* ln_g0    = (const float*)d_in[10];
  const float* ln_b0    = (const float*)d_in[11];
  const float* rel_emb1 = (const float*)d_in[12];
  const float* loop_rel1= (const float*)d_in[13];
  const float* w_loop1  = (const float*)d_in[14];
  const float* w_in1    = (const float*)d_in[15];
  const float* w_out1   = (const float*)d_in[16];
  const float* bias1    = (const float*)d_in[17];
  const float* ln_g1    = (const float*)d_in[18];
  const float* ln_b1    = (const float*)d_in[19];
  const int* edge_src   = (const int*)d_in[20];
  const int* edge_rel   = (const int*)d_in[21];
  const int* edge_dst   = (const int*)d_in[22];

  // ---- workspace layout, high-water ~63.2 MB ----
  char* ws = (char*)d_ws;
  unsigned short* xbf    = (unsigned short*)ws;              // [0, 25.6M)
  unsigned short* accIbf = (unsigned short*)(ws + 25600000); // [25.6M, 51.2M)
  float* invS    = (float*)(ws + 51200000);
  float* invT    = (float*)(ws + 51600000);
  int*   cntT    = (int*)(ws + 52000000);                    // cnts contiguous 800KB
  int*   cntS    = (int*)(ws + 52400000);
  int*   rowptrT = (int*)(ws + 52800000);                    // N_NODES+1 ints
  int*   rowptrS = (int*)(ws + 53200256);
  int*   bsumsT  = (int*)(ws + 53600512);
  int*   bsumsS  = (int*)(ws + 53604608);
  uint2* payT    = (uint2*)(ws + 53608704);                  // 4.8 MB
  uint2* payS    = (uint2*)(ws + 58408704);                  // 4.8 MB (end ~63.21M)
  float* accO    = (float*)d_out;                            // d_out doubles as accO scratch
  float* out     = (float*)d_out;

  // encoder + type-B embedding -> unified bf16 node table
  enc_gemm<<<(N_TYPE_A + 63) / 64, 256, 0, stream>>>(x_typeA, W_mlp, b_mlp, xbf);
  embB_copy<<<6250, 256, 0, stream>>>(emb_B, xbf + (size_t)N_TYPE_A * DD);

  // ---- build CSR (both directions), layer-invariant ----
  hipMemsetAsync(cntT, 0, 2 * N_NODES * sizeof(int), stream);
  deg_count<<<(N_EDGES + 255) / 256, 256, 0, stream>>>(edge_src, edge_dst, cntS, cntT);
  inv_kernel<<<SCAN_NBLK, 256, 0, stream>>>(cntS, cntT, invS, invT);
  scan1<<<SCAN_NBLK, 256, 0, stream>>>(cntT, rowptrT, bsumsT);
  scan1<<<SCAN_NBLK, 256, 0, stream>>>(cntS, rowptrS, bsumsS);
  scan2<<<1, 512, 0, stream>>>(bsumsT);
  scan2<<<1, 512, 0, stream>>>(bsumsS);
  scan3<<<SCAN_NBLK, 256, 0, stream>>>(rowptrT, bsumsT);
  scan3<<<SCAN_NBLK, 256, 0, stream>>>(rowptrS, bsumsS);
  hipMemsetAsync(cntT, 0, 2 * N_NODES * sizeof(int), stream);
  fill_kernel<<<(N_EDGES + 255) / 256, 256, 0, stream>>>(
      edge_src, edge_rel, edge_dst, invS, invT, rowptrT, rowptrS, cntT, cntS, payT, payS);

  // ---- two CompGCN layers ----
  for (int layer = 0; layer < 2; ++layer) {
    agg_kernel<<<N_NODES / 4, 256, 0, stream>>>(
        xbf, layer ? rel_emb1 : rel_emb0, rowptrT, payT, rowptrS, payS, accO, accIbf);
    if (layer == 0)
      conv_ln<true, true><<<(N_NODES + 63) / 64, 256, 0, stream>>>(
          accO, accIbf, xbf, w_out0, w_in0, w_loop0, loop_rel0, bias0, ln_g0, ln_b0,
          xbf, nullptr);
    else
      conv_ln<false, false><<<(N_NODES + 63) / 64, 256, 0, stream>>>(
          accO, accIbf, xbf, w_out1, w_in1, w_loop1, loop_rel1, bias1, ln_g1, ln_b1,
          nullptr, out);
  }
}

// Round 5
// 744.015 us; speedup vs baseline: 3.5811x; 1.2583x over previous
//
#include <hip/hip_runtime.h>
#include <hip/hip_bf16.h>

#define N_NODES   100000
#define N_TYPE_A  50000
#define N_EDGES   600000
#define D_IN      256
#define DD        128
#define LN_EPS    1e-5f
#define SCAN_NBLK 391   // ceil(N_NODES/256)

typedef short bf16x8 __attribute__((ext_vector_type(8)));
typedef float f32x4  __attribute__((ext_vector_type(4)));

__device__ __forceinline__ float bf2f(unsigned short u) {
  unsigned v = ((unsigned)u) << 16;
  return __builtin_bit_cast(float, v);
}
__device__ __forceinline__ unsigned short f2bf(float f) {
  unsigned u = __builtin_bit_cast(unsigned, f);
  u += 0x7FFFu + ((u >> 16) & 1u);
  return (unsigned short)(u >> 16);
}

// ---------------- Encoder: x[0:50000] = x_typeA @ W_mlp.T + b_mlp (bf16 out) ----------------
__global__ __launch_bounds__(256) void enc_gemm(const float* __restrict__ A,
                                                const float* __restrict__ W,
                                                const float* __restrict__ bias,
                                                unsigned short* __restrict__ xout) {
  int wave = threadIdx.x >> 6, lane = threadIdx.x & 63;
  int l15 = lane & 15, lhi = lane >> 4;
  int r0 = blockIdx.x * 64 + wave * 16;
  f32x4 acc[8];
#pragma unroll
  for (int i = 0; i < 8; ++i) acc[i] = (f32x4){0.f, 0.f, 0.f, 0.f};
  int rowA = r0 + l15; if (rowA >= N_TYPE_A) rowA = N_TYPE_A - 1;
#pragma unroll
  for (int kk = 0; kk < 8; ++kk) {
    int kbase = kk * 32 + lhi * 8;
    const float* ap = A + (size_t)rowA * D_IN + kbase;
    float4 a0 = *(const float4*)ap; float4 a1 = *(const float4*)(ap + 4);
    bf16x8 af;
    af[0]=f2bf(a0.x); af[1]=f2bf(a0.y); af[2]=f2bf(a0.z); af[3]=f2bf(a0.w);
    af[4]=f2bf(a1.x); af[5]=f2bf(a1.y); af[6]=f2bf(a1.z); af[7]=f2bf(a1.w);
#pragma unroll
    for (int nt = 0; nt < 8; ++nt) {
      const float* bp = W + (size_t)(nt * 16 + l15) * D_IN + kbase;
      float4 b0 = *(const float4*)bp; float4 b1 = *(const float4*)(bp + 4);
      bf16x8 bfr;
      bfr[0]=f2bf(b0.x); bfr[1]=f2bf(b0.y); bfr[2]=f2bf(b0.z); bfr[3]=f2bf(b0.w);
      bfr[4]=f2bf(b1.x); bfr[5]=f2bf(b1.y); bfr[6]=f2bf(b1.z); bfr[7]=f2bf(b1.w);
      acc[nt] = __builtin_amdgcn_mfma_f32_16x16x32_bf16(af, bfr, acc[nt], 0, 0, 0);
    }
  }
#pragma unroll
  for (int nt = 0; nt < 8; ++nt) {
    int col = nt * 16 + l15;
    float bv = bias[col];
#pragma unroll
    for (int r = 0; r < 4; ++r) {
      int row = r0 + lhi * 4 + r;
      if (row < N_TYPE_A) xout[(size_t)row * DD + col] = f2bf(acc[nt][r] + bv);
    }
  }
}

// ---------------- emb_B f32 -> bf16 copy into x[50000:] ----------------
__global__ __launch_bounds__(256) void embB_copy(const float* __restrict__ e,
                                                 unsigned short* __restrict__ xout) {
  size_t i = ((size_t)blockIdx.x * 256 + threadIdx.x) * 4;
  float4 v = *(const float4*)(e + i);
  unsigned short* o = xout + i;
  o[0] = f2bf(v.x); o[1] = f2bf(v.y); o[2] = f2bf(v.z); o[3] = f2bf(v.w);
}

// ---------------- weight f32 -> bf16 (one 128x128 matrix per launch) ----------------
__global__ __launch_bounds__(256) void wconv(const float* __restrict__ w,
                                             unsigned short* __restrict__ o) {
  int i = (blockIdx.x * 256 + threadIdx.x) * 4;   // 16 blocks for 16384 elems
  float4 v = *(const float4*)(w + i);
  o[i] = f2bf(v.x); o[i+1] = f2bf(v.y); o[i+2] = f2bf(v.z); o[i+3] = f2bf(v.w);
}

// ---------------- bias_adj = bias - (loop_rel @ wLoop.T)/3 ----------------
__global__ __launch_bounds__(128) void bias_fold(const float* __restrict__ bias,
                                                 const float* __restrict__ loop,
                                                 const float* __restrict__ wLoop,
                                                 float* __restrict__ out) {
  int j = threadIdx.x;
  float s = 0.f;
  for (int k = 0; k < DD; ++k) s += loop[k] * wLoop[j * DD + k];
  out[j] = bias[j] - s * (1.0f / 3.0f);
}

// ---------------- degree count ----------------
__global__ __launch_bounds__(256) void deg_count(const int* __restrict__ es,
                                                 const int* __restrict__ et,
                                                 int* cntS, int* cntT) {
  int e = blockIdx.x * 256 + threadIdx.x;
  if (e < N_EDGES) { atomicAdd(&cntS[es[e]], 1); atomicAdd(&cntT[et[e]], 1); }
}

__global__ __launch_bounds__(256) void inv_kernel(const int* __restrict__ cntS,
                                                  const int* __restrict__ cntT,
                                                  float* __restrict__ invS,
                                                  float* __restrict__ invT) {
  int n = blockIdx.x * 256 + threadIdx.x;
  if (n < N_NODES) {
    int d = cntS[n]; invS[n] = d > 0 ? rsqrtf((float)d) : 0.f;
    int e = cntT[n]; invT[n] = e > 0 ? rsqrtf((float)e) : 0.f;
  }
}

// ---------------- exclusive scan (3 kernels) ----------------
__global__ __launch_bounds__(256) void scan1(const int* __restrict__ cnt,
                                             int* __restrict__ rowptr,
                                             int* __restrict__ bsums) {
  __shared__ int tmp[256];
  int gid = blockIdx.x * 256 + threadIdx.x;
  int v = (gid < N_NODES) ? cnt[gid] : 0;
  tmp[threadIdx.x] = v; __syncthreads();
#pragma unroll
  for (int off = 1; off < 256; off <<= 1) {
    int t = (threadIdx.x >= off) ? tmp[threadIdx.x - off] : 0;
    __syncthreads();
    tmp[threadIdx.x] += t;
    __syncthreads();
  }
  if (gid < N_NODES) rowptr[gid] = tmp[threadIdx.x] - v;  // exclusive within block
  if (threadIdx.x == 255) bsums[blockIdx.x] = tmp[255];
}

__global__ __launch_bounds__(512) void scan2(int* __restrict__ bsums) {
  __shared__ int tmp[512];
  int v = (threadIdx.x < SCAN_NBLK) ? bsums[threadIdx.x] : 0;
  tmp[threadIdx.x] = v; __syncthreads();
#pragma unroll
  for (int off = 1; off < 512; off <<= 1) {
    int t = (threadIdx.x >= off) ? tmp[threadIdx.x - off] : 0;
    __syncthreads();
    tmp[threadIdx.x] += t;
    __syncthreads();
  }
  if (threadIdx.x < SCAN_NBLK) bsums[threadIdx.x] = tmp[threadIdx.x] - v;
}

__global__ __launch_bounds__(256) void scan3(int* __restrict__ rowptr,
                                             const int* __restrict__ bsums) {
  int gid = blockIdx.x * 256 + threadIdx.x;
  if (gid < N_NODES) rowptr[gid] += bsums[blockIdx.x];
  if (gid == 0) rowptr[N_NODES] = N_EDGES;
}

// ---------------- CSR fill: payload = {idx | rel<<17, f32 factor} ----------------
__global__ __launch_bounds__(256) void fill_kernel(const int* __restrict__ es,
                                                   const int* __restrict__ er,
                                                   const int* __restrict__ et,
                                                   const float* __restrict__ invS,
                                                   const float* __restrict__ invT,
                                                   const int* __restrict__ rowptrT,
                                                   const int* __restrict__ rowptrS,
                                                   int* cntT, int* cntS,
                                                   uint2* __restrict__ payT,
                                                   uint2* __restrict__ payS) {
  int e = blockIdx.x * 256 + threadIdx.x;
  if (e >= N_EDGES) return;
  int s = es[e], r = er[e], t = et[e];
  unsigned fb = __builtin_bit_cast(unsigned, invS[s] * invT[t]);
  int pT = rowptrT[t] + atomicAdd(&cntT[t], 1);
  payT[pT] = make_uint2((unsigned)s | ((unsigned)r << 17), fb);
  int pS = rowptrS[s] + atomicAdd(&cntS[s], 1);
  payS[pS] = make_uint2((unsigned)t | ((unsigned)r << 17), fb);
}

// ---------------- gather aggregation: one wave per node, no atomics, 2-way MLP ----------------
__global__ __launch_bounds__(256) void agg_kernel(const unsigned short* __restrict__ x,
                                                  const float* __restrict__ rel,
                                                  const int* __restrict__ rowptrT,
                                                  const uint2* __restrict__ payT,
                                                  const int* __restrict__ rowptrS,
                                                  const uint2* __restrict__ payS,
                                                  float* __restrict__ accO,
                                                  unsigned short* __restrict__ accIbf) {
  int wave = threadIdx.x >> 6, lane = threadIdx.x & 63;
  int n = blockIdx.x * 4 + wave;
  int d = lane * 2;
  // out-direction: edges into n (dst-CSR) -> accO[n]
  float a0 = 0.f, a1 = 0.f, c0 = 0.f, c1 = 0.f;
  int b0 = rowptrT[n], b1 = rowptrT[n + 1];
  int i = b0;
  for (; i + 1 < b1; i += 2) {
    uint2 p = payT[i], q = payT[i + 1];
    int pi = p.x & 131071, pr = p.x >> 17;
    int qi = q.x & 131071, qr = q.x >> 17;
    float pf = __builtin_bit_cast(float, p.y);
    float qf = __builtin_bit_cast(float, q.y);
    ushort2 xp = *(const ushort2*)(x + (size_t)pi * DD + d);
    ushort2 xq = *(const ushort2*)(x + (size_t)qi * DD + d);
    float2 rp = *(const float2*)(rel + (size_t)pr * DD + d);
    float2 rq = *(const float2*)(rel + (size_t)qr * DD + d);
    a0 += (bf2f(xp.x) - rp.x) * pf;  a1 += (bf2f(xp.y) - rp.y) * pf;
    c0 += (bf2f(xq.x) - rq.x) * qf;  c1 += (bf2f(xq.y) - rq.y) * qf;
  }
  if (i < b1) {
    uint2 p = payT[i];
    int pi = p.x & 131071, pr = p.x >> 17;
    float pf = __builtin_bit_cast(float, p.y);
    ushort2 xp = *(const ushort2*)(x + (size_t)pi * DD + d);
    float2 rp = *(const float2*)(rel + (size_t)pr * DD + d);
    a0 += (bf2f(xp.x) - rp.x) * pf;  a1 += (bf2f(xp.y) - rp.y) * pf;
  }
  accO[(size_t)n * DD + d]     = a0 + c0;
  accO[(size_t)n * DD + d + 1] = a1 + c1;
  // in-direction: edges out of n (src-CSR) -> accIbf[n]
  a0 = 0.f; a1 = 0.f; c0 = 0.f; c1 = 0.f;
  b0 = rowptrS[n]; b1 = rowptrS[n + 1];
  i = b0;
  for (; i + 1 < b1; i += 2) {
    uint2 p = payS[i], q = payS[i + 1];
    int pi = p.x & 131071, pr = p.x >> 17;
    int qi = q.x & 131071, qr = q.x >> 17;
    float pf = __builtin_bit_cast(float, p.y);
    float qf = __builtin_bit_cast(float, q.y);
    ushort2 xp = *(const ushort2*)(x + (size_t)pi * DD + d);
    ushort2 xq = *(const ushort2*)(x + (size_t)qi * DD + d);
    float2 rp = *(const float2*)(rel + (size_t)pr * DD + d);
    float2 rq = *(const float2*)(rel + (size_t)qr * DD + d);
    a0 += (bf2f(xp.x) - rp.x) * pf;  a1 += (bf2f(xp.y) - rp.y) * pf;
    c0 += (bf2f(xq.x) - rq.x) * qf;  c1 += (bf2f(xq.y) - rq.y) * qf;
  }
  if (i < b1) {
    uint2 p = payS[i];
    int pi = p.x & 131071, pr = p.x >> 17;
    float pf = __builtin_bit_cast(float, p.y);
    ushort2 xp = *(const ushort2*)(x + (size_t)pi * DD + d);
    float2 rp = *(const float2*)(rel + (size_t)pr * DD + d);
    a0 += (bf2f(xp.x) - rp.x) * pf;  a1 += (bf2f(xp.y) - rp.y) * pf;
  }
  *(ushort2*)(accIbf + (size_t)n * DD + d) = make_ushort2(f2bf(a0 + c0), f2bf(a1 + c1));
}

// ------- per-layer transform: 3 fused GEMMs (K=384, bf16 weights) + biasAdj + [relu] + LN -------
// NOTE: `x` / accO / outf must NOT be __restrict__ — layer0 writes outbf==x (in-place),
// layer1 reads accO==d_out and writes outf==d_out. Per-wave read-before-write on own rows,
// rows disjoint across waves; legal only without restrict's reordering license.
template<bool RELU, bool OUTBF>
__global__ __launch_bounds__(256) void conv_ln(const float* accO,
                                               const unsigned short* accIbf,
                                               const unsigned short* x,
                                               const unsigned short* __restrict__ wOut,
                                               const unsigned short* __restrict__ wIn,
                                               const unsigned short* __restrict__ wLoop,
                                               const float* __restrict__ biasAdj,
                                               const float* __restrict__ g,
                                               const float* __restrict__ bln,
                                               unsigned short* outbf, float* outf) {
  int wave = threadIdx.x >> 6, lane = threadIdx.x & 63;
  int l15 = lane & 15, lhi = lane >> 4;
  int r0 = blockIdx.x * 64 + wave * 16;
  f32x4 acc[8];
#pragma unroll
  for (int i = 0; i < 8; ++i) acc[i] = (f32x4){0.f, 0.f, 0.f, 0.f};
  int rowA = r0 + l15; if (rowA >= N_NODES) rowA = N_NODES - 1;
#pragma unroll
  for (int m = 0; m < 3; ++m) {
    const unsigned short* wmat = (m == 0) ? wOut : ((m == 1) ? wIn : wLoop);
#pragma unroll
    for (int kk = 0; kk < 4; ++kk) {
      int kbase = kk * 32 + lhi * 8;
      bf16x8 af;
      if (m == 0) {
        const float* ap = accO + (size_t)rowA * DD + kbase;
        float4 a0 = *(const float4*)ap; float4 a1 = *(const float4*)(ap + 4);
        af[0]=f2bf(a0.x); af[1]=f2bf(a0.y); af[2]=f2bf(a0.z); af[3]=f2bf(a0.w);
        af[4]=f2bf(a1.x); af[5]=f2bf(a1.y); af[6]=f2bf(a1.z); af[7]=f2bf(a1.w);
      } else if (m == 1) {
        af = *(const bf16x8*)(accIbf + (size_t)rowA * DD + kbase);
      } else {
        af = *(const bf16x8*)(x + (size_t)rowA * DD + kbase);   // loop_rel folded into biasAdj
      }
#pragma unroll
      for (int nt = 0; nt < 8; ++nt) {
        bf16x8 bfr = *(const bf16x8*)(wmat + (size_t)(nt * 16 + l15) * DD + kbase);
        acc[nt] = __builtin_amdgcn_mfma_f32_16x16x32_bf16(af, bfr, acc[nt], 0, 0, 0);
      }
    }
  }
  // epilogue: v = acc/3 + biasAdj ; [relu] ; LayerNorm per row (128 cols)
  float bv[8], gv[8], bb[8];
#pragma unroll
  for (int nt = 0; nt < 8; ++nt) {
    int col = nt * 16 + l15;
    bv[nt] = biasAdj[col]; gv[nt] = g[col]; bb[nt] = bln[col];
  }
  const float third = 1.0f / 3.0f;
  float s0[4] = {0.f, 0.f, 0.f, 0.f}, s1[4] = {0.f, 0.f, 0.f, 0.f};
#pragma unroll
  for (int nt = 0; nt < 8; ++nt)
#pragma unroll
    for (int r = 0; r < 4; ++r) {
      float v = acc[nt][r] * third + bv[nt];
      if (RELU) v = fmaxf(v, 0.f);
      acc[nt][r] = v;
      s0[r] += v; s1[r] += v * v;
    }
#pragma unroll
  for (int off = 1; off < 16; off <<= 1)
#pragma unroll
    for (int r = 0; r < 4; ++r) {
      s0[r] += __shfl_xor(s0[r], off);
      s1[r] += __shfl_xor(s1[r], off);
    }
  float mu[4], rstd[4];
#pragma unroll
  for (int r = 0; r < 4; ++r) {
    mu[r] = s0[r] * (1.f / 128.f);
    float var = s1[r] * (1.f / 128.f) - mu[r] * mu[r];
    rstd[r] = rsqrtf(var + LN_EPS);
  }
#pragma unroll
  for (int nt = 0; nt < 8; ++nt) {
    int col = nt * 16 + l15;
#pragma unroll
    for (int r = 0; r < 4; ++r) {
      int row = r0 + lhi * 4 + r;
      if (row < N_NODES) {
        float y = (acc[nt][r] - mu[r]) * rstd[r] * gv[nt] + bb[nt];
        if (OUTBF) outbf[(size_t)row * DD + col] = f2bf(y);
        else       outf[(size_t)row * DD + col]  = y;
      }
    }
  }
}

extern "C" void kernel_launch(void* const* d_in, const int* in_sizes, int n_in,
                              void* d_out, int out_size, void* d_ws, size_t ws_size,
                              hipStream_t stream) {
  const float* x_typeA  = (const float*)d_in[0];
  const float* W_mlp    = (const float*)d_in[1];
  const float* b_mlp    = (const float*)d_in[2];
  const float* emb_B    = (const float*)d_in[3];
  const float* rel_emb0 = (const float*)d_in[4];
  const float* loop_rel0= (const float*)d_in[5];
  const float* w_loop0  = (const float*)d_in[6];
  const float* w_in0    = (const float*)d_in[7];
  const float* w_out0   = (const float*)d_in[8];
  const float* bias0    = (const float*)d_in[9];
  const float* ln_g0    = (const float*)d_in[10];
  const float* ln_b0    = (const float*)d_in[11];
  const float* rel_emb1 = (const float*)d_in[12];
  const float* loop_rel1= (const float*)d_in[13];
  const float* w_loop1  = (const float*)d_in[14];
  const float* w_in1    = (const float*)d_in[15];
  const float* w_out1   = (const float*)d_in[16];
  const float* bias1    = (const float*)d_in[17];
  const float* ln_g1    = (const float*)d_in[18];
  const float* ln_b1    = (const float*)d_in[19];
  const int* edge_src   = (const int*)d_in[20];
  const int* edge_rel   = (const int*)d_in[21];
  const int* edge_dst   = (const int*)d_in[22];

  // ---- workspace layout, high-water ~63.4 MB ----
  char* ws = (char*)d_ws;
  unsigned short* xbf    = (unsigned short*)ws;              // [0, 25.6M)
  unsigned short* accIbf = (unsigned short*)(ws + 25600000); // [25.6M, 51.2M)
  float* invS    = (float*)(ws + 51200000);
  float* invT    = (float*)(ws + 51600000);
  int*   cntT    = (int*)(ws + 52000000);
  int*   cntS    = (int*)(ws + 52400000);
  int*   rowptrT = (int*)(ws + 52800000);
  int*   rowptrS = (int*)(ws + 53200256);
  int*   bsumsT  = (int*)(ws + 53600512);
  int*   bsumsS  = (int*)(ws + 53604608);
  uint2* payT    = (uint2*)(ws + 53608704);                  // 4.8 MB
  uint2* payS    = (uint2*)(ws + 58408704);                  // 4.8 MB
  unsigned short* wbf = (unsigned short*)(ws + 63208704);    // 6 x 32 KB bf16 weights
  float* biasAdj0 = (float*)(ws + 63405312);                 // 512 B
  float* biasAdj1 = (float*)(ws + 63405824);                 // end ~63.41M
  float* accO    = (float*)d_out;                            // d_out doubles as accO scratch
  float* out     = (float*)d_out;

  unsigned short* wOutbf0 = wbf;
  unsigned short* wInbf0  = wbf + 16384;
  unsigned short* wLoopbf0= wbf + 32768;
  unsigned short* wOutbf1 = wbf + 49152;
  unsigned short* wInbf1  = wbf + 65536;
  unsigned short* wLoopbf1= wbf + 81920;

  // encoder + type-B embedding -> unified bf16 node table
  enc_gemm<<<(N_TYPE_A + 63) / 64, 256, 0, stream>>>(x_typeA, W_mlp, b_mlp, xbf);
  embB_copy<<<6250, 256, 0, stream>>>(emb_B, xbf + (size_t)N_TYPE_A * DD);

  // weights -> bf16; fold loop_rel@wLoop.T into bias
  wconv<<<16, 256, 0, stream>>>(w_out0, wOutbf0);
  wconv<<<16, 256, 0, stream>>>(w_in0,  wInbf0);
  wconv<<<16, 256, 0, stream>>>(w_loop0, wLoopbf0);
  wconv<<<16, 256, 0, stream>>>(w_out1, wOutbf1);
  wconv<<<16, 256, 0, stream>>>(w_in1,  wInbf1);
  wconv<<<16, 256, 0, stream>>>(w_loop1, wLoopbf1);
  bias_fold<<<1, 128, 0, stream>>>(bias0, loop_rel0, w_loop0, biasAdj0);
  bias_fold<<<1, 128, 0, stream>>>(bias1, loop_rel1, w_loop1, biasAdj1);

  // ---- build CSR (both directions), layer-invariant ----
  hipMemsetAsync(cntT, 0, 2 * N_NODES * sizeof(int), stream);
  deg_count<<<(N_EDGES + 255) / 256, 256, 0, stream>>>(edge_src, edge_dst, cntS, cntT);
  inv_kernel<<<SCAN_NBLK, 256, 0, stream>>>(cntS, cntT, invS, invT);
  scan1<<<SCAN_NBLK, 256, 0, stream>>>(cntT, rowptrT, bsumsT);
  scan1<<<SCAN_NBLK, 256, 0, stream>>>(cntS, rowptrS, bsumsS);
  scan2<<<1, 512, 0, stream>>>(bsumsT);
  scan2<<<1, 512, 0, stream>>>(bsumsS);
  scan3<<<SCAN_NBLK, 256, 0, stream>>>(rowptrT, bsumsT);
  scan3<<<SCAN_NBLK, 256, 0, stream>>>(rowptrS, bsumsS);
  hipMemsetAsync(cntT, 0, 2 * N_NODES * sizeof(int), stream);
  fill_kernel<<<(N_EDGES + 255) / 256, 256, 0, stream>>>(
      edge_src, edge_rel, edge_dst, invS, invT, rowptrT, rowptrS, cntT, cntS, payT, payS);

  // ---- two CompGCN layers ----
  for (int layer = 0; layer < 2; ++layer) {
    agg_kernel<<<N_NODES / 4, 256, 0, stream>>>(
        xbf, layer ? rel_emb1 : rel_emb0, rowptrT, payT, rowptrS, payS, accO, accIbf);
    if (layer == 0)
      conv_ln<true, true><<<(N_NODES + 63) / 64, 256, 0, stream>>>(
          accO, accIbf, xbf, wOutbf0, wInbf0, wLoopbf0, biasAdj0, ln_g0, ln_b0,
          xbf, nullptr);
    else
      conv_ln<false, false><<<(N_NODES + 63) / 64, 256, 0, stream>>>(
          accO, accIbf, xbf, wOutbf1, wInbf1, wLoopbf1, biasAdj1, ln_g1, ln_b1,
          nullptr, out);
  }
}

// Round 8
// 685.009 us; speedup vs baseline: 3.8896x; 1.0861x over previous
//
#include <hip/hip_runtime.h>
#include <hip/hip_bf16.h>

#define N_NODES   100000
#define N_TYPE_A  50000
#define N_EDGES   600000
#define D_IN      256
#define DD        128
#define LN_EPS    1e-5f
#define SCAN_NBLK 391   // ceil(N_NODES/256)

typedef short bf16x8 __attribute__((ext_vector_type(8)));
typedef float f32x4  __attribute__((ext_vector_type(4)));

__device__ __forceinline__ float bf2f(unsigned short u) {
  unsigned v = ((unsigned)u) << 16;
  return __builtin_bit_cast(float, v);
}
__device__ __forceinline__ unsigned short f2bf(float f) {
  unsigned u = __builtin_bit_cast(unsigned, f);
  u += 0x7FFFu + ((u >> 16) & 1u);
  return (unsigned short)(u >> 16);
}

// ---------------- fused prep: 7 weight f32->bf16 conversions + 2 bias folds ----------------
struct PrepArgs {
  const float* src[7];          // W_mlp(32768 elems), wOut0,wIn0,wLoop0,wOut1,wIn1,wLoop1 (16384 ea)
  unsigned short* dst[7];
  const float* bias[2];
  const float* loop[2];
  const float* wloop[2];
  float* biasAdj[2];
};

__global__ __launch_bounds__(256) void prep_kernel(PrepArgs p) {
  int b = blockIdx.x;
  if (b < 128) {
    int idx = (b * 256 + threadIdx.x) * 4;    // 131072 f32 elems total
    int m, off;
    if (idx < 32768) { m = 0; off = idx; }
    else { int t = idx - 32768; m = 1 + t / 16384; off = t % 16384; }
    const float* s = p.src[m];
    unsigned short* d = p.dst[m];
    float4 v = *(const float4*)(s + off);
    d[off] = f2bf(v.x); d[off+1] = f2bf(v.y); d[off+2] = f2bf(v.z); d[off+3] = f2bf(v.w);
  } else if (b < 130) {
    int L = b - 128;
    if (threadIdx.x < DD) {
      int j = threadIdx.x;
      float s = 0.f;
      for (int k = 0; k < DD; ++k) s += p.loop[L][k] * p.wloop[L][j * DD + k];
      p.biasAdj[L][j] = p.bias[L][j] - s * (1.0f / 3.0f);
    }
  }
}

// ---------------- Encoder: x[0:50000] = x_typeA @ W_mlp.T + b_mlp (bf16 weights) ----------------
__global__ __launch_bounds__(256) void enc_gemm(const float* __restrict__ A,
                                                const unsigned short* __restrict__ Wbf,
                                                const float* __restrict__ bias,
                                                unsigned short* __restrict__ xout) {
  int wave = threadIdx.x >> 6, lane = threadIdx.x & 63;
  int l15 = lane & 15, lhi = lane >> 4;
  int r0 = blockIdx.x * 64 + wave * 16;
  f32x4 acc[8];
#pragma unroll
  for (int i = 0; i < 8; ++i) acc[i] = (f32x4){0.f, 0.f, 0.f, 0.f};
  int rowA = r0 + l15; if (rowA >= N_TYPE_A) rowA = N_TYPE_A - 1;
#pragma unroll
  for (int kk = 0; kk < 8; ++kk) {
    int kbase = kk * 32 + lhi * 8;
    const float* ap = A + (size_t)rowA * D_IN + kbase;
    float4 a0 = *(const float4*)ap; float4 a1 = *(const float4*)(ap + 4);
    bf16x8 af;
    af[0]=f2bf(a0.x); af[1]=f2bf(a0.y); af[2]=f2bf(a0.z); af[3]=f2bf(a0.w);
    af[4]=f2bf(a1.x); af[5]=f2bf(a1.y); af[6]=f2bf(a1.z); af[7]=f2bf(a1.w);
#pragma unroll
    for (int nt = 0; nt < 8; ++nt) {
      bf16x8 bfr = *(const bf16x8*)(Wbf + (size_t)(nt * 16 + l15) * D_IN + kbase);
      acc[nt] = __builtin_amdgcn_mfma_f32_16x16x32_bf16(af, bfr, acc[nt], 0, 0, 0);
    }
  }
#pragma unroll
  for (int nt = 0; nt < 8; ++nt) {
    int col = nt * 16 + l15;
    float bv = bias[col];
#pragma unroll
    for (int r = 0; r < 4; ++r) {
      int row = r0 + lhi * 4 + r;
      if (row < N_TYPE_A) xout[(size_t)row * DD + col] = f2bf(acc[nt][r] + bv);
    }
  }
}

// ---------------- emb_B f32 -> bf16 copy into x[50000:] ----------------
__global__ __launch_bounds__(256) void embB_copy(const float* __restrict__ e,
                                                 unsigned short* __restrict__ xout) {
  size_t i = ((size_t)blockIdx.x * 256 + threadIdx.x) * 4;
  float4 v = *(const float4*)(e + i);
  unsigned short* o = xout + i;
  o[0] = f2bf(v.x); o[1] = f2bf(v.y); o[2] = f2bf(v.z); o[3] = f2bf(v.w);
}

// ---------------- degree count ----------------
__global__ __launch_bounds__(256) void deg_count(const int* __restrict__ es,
                                                 const int* __restrict__ et,
                                                 int* cntS, int* cntT) {
  int e = blockIdx.x * 256 + threadIdx.x;
  if (e < N_EDGES) { atomicAdd(&cntS[es[e]], 1); atomicAdd(&cntT[et[e]], 1); }
}

// ---------------- exclusive scan, both CSRs per launch ----------------
__global__ __launch_bounds__(256) void scan1(const int* __restrict__ cntT,
                                             const int* __restrict__ cntS,
                                             int* __restrict__ rowptrT,
                                             int* __restrict__ rowptrS,
                                             int* __restrict__ bsumsT,
                                             int* __restrict__ bsumsS) {
  __shared__ int tmp[256];
  bool isT = blockIdx.x < SCAN_NBLK;
  int blk = isT ? blockIdx.x : blockIdx.x - SCAN_NBLK;
  const int* cnt = isT ? cntT : cntS;
  int* rowptr = isT ? rowptrT : rowptrS;
  int* bsums  = isT ? bsumsT : bsumsS;
  int gid = blk * 256 + threadIdx.x;
  int v = (gid < N_NODES) ? cnt[gid] : 0;
  tmp[threadIdx.x] = v; __syncthreads();
#pragma unroll
  for (int off = 1; off < 256; off <<= 1) {
    int t = (threadIdx.x >= off) ? tmp[threadIdx.x - off] : 0;
    __syncthreads();
    tmp[threadIdx.x] += t;
    __syncthreads();
  }
  if (gid < N_NODES) rowptr[gid] = tmp[threadIdx.x] - v;
  if (threadIdx.x == 255) bsums[blk] = tmp[255];
}

__global__ __launch_bounds__(512) void scan2(int* __restrict__ bsumsT,
                                             int* __restrict__ bsumsS) {
  __shared__ int tmp[512];
  int* bsums = blockIdx.x ? bsumsS : bsumsT;
  int v = (threadIdx.x < SCAN_NBLK) ? bsums[threadIdx.x] : 0;
  tmp[threadIdx.x] = v; __syncthreads();
#pragma unroll
  for (int off = 1; off < 512; off <<= 1) {
    int t = (threadIdx.x >= off) ? tmp[threadIdx.x - off] : 0;
    __syncthreads();
    tmp[threadIdx.x] += t;
    __syncthreads();
  }
  if (threadIdx.x < SCAN_NBLK) bsums[threadIdx.x] = tmp[threadIdx.x] - v;
}

// ---------------- scan3 + inv-sqrt + cnt rezero (cursor for fill) ----------------
__global__ __launch_bounds__(256) void scan3(int* __restrict__ rowptrT,
                                             int* __restrict__ rowptrS,
                                             const int* __restrict__ bsumsT,
                                             const int* __restrict__ bsumsS,
                                             int* __restrict__ cntT,
                                             int* __restrict__ cntS,
                                             float* __restrict__ invT,
                                             float* __restrict__ invS) {
  bool isT = blockIdx.x < SCAN_NBLK;
  int blk = isT ? blockIdx.x : blockIdx.x - SCAN_NBLK;
  int gid = blk * 256 + threadIdx.x;
  if (gid < N_NODES) {
    if (isT) {
      rowptrT[gid] += bsumsT[blk];
      int c = cntT[gid]; invT[gid] = c > 0 ? rsqrtf((float)c) : 0.f; cntT[gid] = 0;
      if (gid == 0) rowptrT[N_NODES] = N_EDGES;
    } else {
      rowptrS[gid] += bsumsS[blk];
      int c = cntS[gid]; invS[gid] = c > 0 ? rsqrtf((float)c) : 0.f; cntS[gid] = 0;
      if (gid == 0) rowptrS[N_NODES] = N_EDGES;
    }
  }
}

// ---------------- CSR fill: payload = {idx | rel<<17, f32 factor} ----------------
__global__ __launch_bounds__(256) void fill_kernel(const int* __restrict__ es,
                                                   const int* __restrict__ er,
                                                   const int* __restrict__ et,
                                                   const float* __restrict__ invS,
                                                   const float* __restrict__ invT,
                                                   const int* __restrict__ rowptrT,
                                                   const int* __restrict__ rowptrS,
                                                   int* cntT, int* cntS,
                                                   uint2* __restrict__ payT,
                                                   uint2* __restrict__ payS) {
  int e = blockIdx.x * 256 + threadIdx.x;
  if (e >= N_EDGES) return;
  int s = es[e], r = er[e], t = et[e];
  unsigned fb = __builtin_bit_cast(unsigned, invS[s] * invT[t]);
  int pT = rowptrT[t] + atomicAdd(&cntT[t], 1);
  payT[pT] = make_uint2((unsigned)s | ((unsigned)r << 17), fb);
  int pS = rowptrS[s] + atomicAdd(&cntS[s], 1);
  payS[pS] = make_uint2((unsigned)t | ((unsigned)r << 17), fb);
}

// ------- gather aggregation: one wave per node, no atomics, 2-way unroll -------
template<bool OBF>
__global__ __launch_bounds__(256) void agg_kernel(const unsigned short* __restrict__ x,
                                                  const float* __restrict__ rel,
                                                  const int* __restrict__ rowptrT,
                                                  const uint2* __restrict__ payT,
                                                  const int* __restrict__ rowptrS,
                                                  const uint2* __restrict__ payS,
                                                  float* accOf, unsigned short* accObf,
                                                  unsigned short* __restrict__ accIbf) {
  int wave = threadIdx.x >> 6, lane = threadIdx.x & 63;
  int n = blockIdx.x * 4 + wave;
  int d = lane * 2;
  // ---- out-direction: dst-CSR -> accO[n] ----
  float a0 = 0.f, a1 = 0.f, c0 = 0.f, c1 = 0.f;
  int b0 = rowptrT[n], b1 = rowptrT[n + 1];
  int i = b0;
  for (; i + 1 < b1; i += 2) {
    uint2 p = payT[i], q = payT[i + 1];
    int pi = p.x & 131071, pr = p.x >> 17;
    int qi = q.x & 131071, qr = q.x >> 17;
    float pf = __builtin_bit_cast(float, p.y);
    float qf = __builtin_bit_cast(float, q.y);
    ushort2 xp = *(const ushort2*)(x + (size_t)pi * DD + d);
    ushort2 xq = *(const ushort2*)(x + (size_t)qi * DD + d);
    float2 rp = *(const float2*)(rel + (size_t)pr * DD + d);
    float2 rq = *(const float2*)(rel + (size_t)qr * DD + d);
    a0 += (bf2f(xp.x) - rp.x) * pf;  a1 += (bf2f(xp.y) - rp.y) * pf;
    c0 += (bf2f(xq.x) - rq.x) * qf;  c1 += (bf2f(xq.y) - rq.y) * qf;
  }
  if (i < b1) {
    uint2 p = payT[i];
    int pi = p.x & 131071, pr = p.x >> 17;
    float pf = __builtin_bit_cast(float, p.y);
    ushort2 xp = *(const ushort2*)(x + (size_t)pi * DD + d);
    float2 rp = *(const float2*)(rel + (size_t)pr * DD + d);
    a0 += (bf2f(xp.x) - rp.x) * pf;  a1 += (bf2f(xp.y) - rp.y) * pf;
  }
  a0 += c0; a1 += c1;
  if constexpr (OBF) {
    *(ushort2*)(accObf + (size_t)n * DD + d) = make_ushort2(f2bf(a0), f2bf(a1));
  } else {
    accOf[(size_t)n * DD + d]     = a0;
    accOf[(size_t)n * DD + d + 1] = a1;
  }
  // ---- in-direction: src-CSR -> accIbf[n] ----
  a0 = 0.f; a1 = 0.f; c0 = 0.f; c1 = 0.f;
  b0 = rowptrS[n]; b1 = rowptrS[n + 1];
  i = b0;
  for (; i + 1 < b1; i += 2) {
    uint2 p = payS[i], q = payS[i + 1];
    int pi = p.x & 131071, pr = p.x >> 17;
    int qi = q.x & 131071, qr = q.x >> 17;
    float pf = __builtin_bit_cast(float, p.y);
    float qf = __builtin_bit_cast(float, q.y);
    ushort2 xp = *(const ushort2*)(x + (size_t)pi * DD + d);
    ushort2 xq = *(const ushort2*)(x + (size_t)qi * DD + d);
    float2 rp = *(const float2*)(rel + (size_t)pr * DD + d);
    float2 rq = *(const float2*)(rel + (size_t)qr * DD + d);
    a0 += (bf2f(xp.x) - rp.x) * pf;  a1 += (bf2f(xp.y) - rp.y) * pf;
    c0 += (bf2f(xq.x) - rq.x) * qf;  c1 += (bf2f(xq.y) - rq.y) * qf;
  }
  if (i < b1) {
    uint2 p = payS[i];
    int pi = p.x & 131071, pr = p.x >> 17;
    float pf = __builtin_bit_cast(float, p.y);
    ushort2 xp = *(const ushort2*)(x + (size_t)pi * DD + d);
    float2 rp = *(const float2*)(rel + (size_t)pr * DD + d);
    a0 += (bf2f(xp.x) - rp.x) * pf;  a1 += (bf2f(xp.y) - rp.y) * pf;
  }
  *(ushort2*)(accIbf + (size_t)n * DD + d) = make_ushort2(f2bf(a0 + c0), f2bf(a1 + c1));
}

// ------- per-layer transform: 3 fused GEMMs (K=384, bf16) + biasAdj + [relu] + LN -------
// NOTE: x / accOf / accObf / outf are NOT __restrict__ — layer0 writes outbf==x (in-place),
// layer1 reads accOf==d_out and writes outf==d_out. Per-wave read-before-write on own rows,
// rows disjoint across waves; legal only without restrict's reordering license.
template<bool RELU, bool OUTBF, bool A0BF>
__global__ __launch_bounds__(256) void conv_ln(const float* accOf,
                                               const unsigned short* accObf,
                                               const unsigned short* accIbf,
                                               const unsigned short* x,
                                               const unsigned short* __restrict__ wOut,
                                               const unsigned short* __restrict__ wIn,
                                               const unsigned short* __restrict__ wLoop,
                                               const float* __restrict__ biasAdj,
                                               const float* __restrict__ g,
                                               const float* __restrict__ bln,
                                               unsigned short* outbf, float* outf) {
  int wave = threadIdx.x >> 6, lane = threadIdx.x & 63;
  int l15 = lane & 15, lhi = lane >> 4;
  int r0 = blockIdx.x * 64 + wave * 16;
  f32x4 acc[8];
#pragma unroll
  for (int i = 0; i < 8; ++i) acc[i] = (f32x4){0.f, 0.f, 0.f, 0.f};
  int rowA = r0 + l15; if (rowA >= N_NODES) rowA = N_NODES - 1;
#pragma unroll
  for (int m = 0; m < 3; ++m) {
    const unsigned short* wmat = (m == 0) ? wOut : ((m == 1) ? wIn : wLoop);
#pragma unroll
    for (int kk = 0; kk < 4; ++kk) {
      int kbase = kk * 32 + lhi * 8;
      bf16x8 af;
      if (m == 0) {
        if constexpr (A0BF) {
          af = *(const bf16x8*)(accObf + (size_t)rowA * DD + kbase);
        } else {
          const float* ap = accOf + (size_t)rowA * DD + kbase;
          float4 a0 = *(const float4*)ap; float4 a1 = *(const float4*)(ap + 4);
          af[0]=f2bf(a0.x); af[1]=f2bf(a0.y); af[2]=f2bf(a0.z); af[3]=f2bf(a0.w);
          af[4]=f2bf(a1.x); af[5]=f2bf(a1.y); af[6]=f2bf(a1.z); af[7]=f2bf(a1.w);
        }
      } else if (m == 1) {
        af = *(const bf16x8*)(accIbf + (size_t)rowA * DD + kbase);
      } else {
        af = *(const bf16x8*)(x + (size_t)rowA * DD + kbase);   // loop_rel folded into biasAdj
      }
#pragma unroll
      for (int nt = 0; nt < 8; ++nt) {
        bf16x8 bfr = *(const bf16x8*)(wmat + (size_t)(nt * 16 + l15) * DD + kbase);
        acc[nt] = __builtin_amdgcn_mfma_f32_16x16x32_bf16(af, bfr, acc[nt], 0, 0, 0);
      }
    }
  }
  float bv[8], gv[8], bb[8];
#pragma unroll
  for (int nt = 0; nt < 8; ++nt) {
    int col = nt * 16 + l15;
    bv[nt] = biasAdj[col]; gv[nt] = g[col]; bb[nt] = bln[col];
  }
  const float third = 1.0f / 3.0f;
  float s0[4] = {0.f, 0.f, 0.f, 0.f}, s1[4] = {0.f, 0.f, 0.f, 0.f};
#pragma unroll
  for (int nt = 0; nt < 8; ++nt)
#pragma unroll
    for (int r = 0; r < 4; ++r) {
      float v = acc[nt][r] * third + bv[nt];
      if (RELU) v = fmaxf(v, 0.f);
      acc[nt][r] = v;
      s0[r] += v; s1[r] += v * v;
    }
#pragma unroll
  for (int off = 1; off < 16; off <<= 1)
#pragma unroll
    for (int r = 0; r < 4; ++r) {
      s0[r] += __shfl_xor(s0[r], off);
      s1[r] += __shfl_xor(s1[r], off);
    }
  float mu[4], rstd[4];
#pragma unroll
  for (int r = 0; r < 4; ++r) {
    mu[r] = s0[r] * (1.f / 128.f);
    float var = s1[r] * (1.f / 128.f) - mu[r] * mu[r];
    rstd[r] = rsqrtf(var + LN_EPS);
  }
#pragma unroll
  for (int nt = 0; nt < 8; ++nt) {
    int col = nt * 16 + l15;
#pragma unroll
    for (int r = 0; r < 4; ++r) {
      int row = r0 + lhi * 4 + r;
      if (row < N_NODES) {
        float y = (acc[nt][r] - mu[r]) * rstd[r] * gv[nt] + bb[nt];
        if (OUTBF) outbf[(size_t)row * DD + col] = f2bf(y);
        else       outf[(size_t)row * DD + col]  = y;
      }
    }
  }
}

extern "C" void kernel_launch(void* const* d_in, const int* in_sizes, int n_in,
                              void* d_out, int out_size, void* d_ws, size_t ws_size,
                              hipStream_t stream) {
  const float* x_typeA  = (const float*)d_in[0];
  const float* W_mlp    = (const float*)d_in[1];
  const float* b_mlp    = (const float*)d_in[2];
  const float* emb_B    = (const float*)d_in[3];
  const float* rel_emb0 = (const float*)d_in[4];
  const float* loop_rel0= (const float*)d_in[5];
  const float* w_loop0  = (const float*)d_in[6];
  const float* w_in0    = (const float*)d_in[7];
  const float* w_out0   = (const float*)d_in[8];
  const float* bias0    = (const float*)d_in[9];
  const float* ln_g0    = (const float*)d_in[10];
  const float* ln_b0    = (const float*)d_in[11];
  const float* rel_emb1 = (const float*)d_in[12];
  const float* loop_rel1= (const float*)d_in[13];
  const float* w_loop1  = (const float*)d_in[14];
  const float* w_in1    = (const float*)d_in[15];
  const float* w_out1   = (const float*)d_in[16];
  const float* bias1    = (const float*)d_in[17];
  const float* ln_g1    = (const float*)d_in[18];
  const float* ln_b1    = (const float*)d_in[19];
  const int* edge_src   = (const int*)d_in[20];
  const int* edge_rel   = (const int*)d_in[21];
  const int* edge_dst   = (const int*)d_in[22];

  // ---- workspace layout, high-water ~63.47 MB ----
  // wbf holds 7 bf16 matrices = 65536 B (W_mlp, 32768 elems) + 6*32768 B = 262144 B total.
  // (Round-6/7 NaN bug: biasAdj was placed at wbf+229376, INSIDE wLoopbf1. Fixed: +262144.)
  char* ws = (char*)d_ws;
  unsigned short* xbf    = (unsigned short*)ws;              // [0, 25.6M)
  unsigned short* accIbf = (unsigned short*)(ws + 25600000); // [25.6M, 51.2M)
  float* invS    = (float*)(ws + 51200000);
  float* invT    = (float*)(ws + 51600000);
  int*   cntT    = (int*)(ws + 52000000);                    // cntT+cntS contiguous 800 KB
  int*   cntS    = (int*)(ws + 52400000);
  int*   rowptrT = (int*)(ws + 52800000);
  int*   rowptrS = (int*)(ws + 53200256);
  int*   bsumsT  = (int*)(ws + 53600512);
  int*   bsumsS  = (int*)(ws + 53604608);
  uint2* payT    = (uint2*)(ws + 53608704);                  // 4.8 MB
  uint2* payS    = (uint2*)(ws + 58408704);                  // 4.8 MB
  unsigned short* wbf = (unsigned short*)(ws + 63208704);    // [63208704, 63470848)
  float* biasAdj0 = (float*)(ws + 63470848);                 // past wbf end
  float* biasAdj1 = (float*)(ws + 63471360);                 // end 63471872 (~63.47M)
  float* accOf   = (float*)d_out;                            // layer1 f32 acc (in-place safe)
  unsigned short* accObf = (unsigned short*)d_out;           // layer0 bf16 acc (conv0 writes xbf only)
  float* out     = (float*)d_out;

  unsigned short* WmlpBf  = wbf;                 // 32768 elems
  unsigned short* wOutbf0 = wbf + 32768;
  unsigned short* wInbf0  = wbf + 49152;
  unsigned short* wLoopbf0= wbf + 65536;
  unsigned short* wOutbf1 = wbf + 81920;
  unsigned short* wInbf1  = wbf + 98304;
  unsigned short* wLoopbf1= wbf + 114688;        // ends at elem 131072 = byte 262144

  // ---- fused prep: weights -> bf16, bias folds ----
  PrepArgs pa;
  pa.src[0] = W_mlp;  pa.dst[0] = WmlpBf;
  pa.src[1] = w_out0; pa.dst[1] = wOutbf0;
  pa.src[2] = w_in0;  pa.dst[2] = wInbf0;
  pa.src[3] = w_loop0;pa.dst[3] = wLoopbf0;
  pa.src[4] = w_out1; pa.dst[4] = wOutbf1;
  pa.src[5] = w_in1;  pa.dst[5] = wInbf1;
  pa.src[6] = w_loop1;pa.dst[6] = wLoopbf1;
  pa.bias[0] = bias0; pa.bias[1] = bias1;
  pa.loop[0] = loop_rel0; pa.loop[1] = loop_rel1;
  pa.wloop[0] = w_loop0;  pa.wloop[1] = w_loop1;
  pa.biasAdj[0] = biasAdj0; pa.biasAdj[1] = biasAdj1;
  prep_kernel<<<130, 256, 0, stream>>>(pa);

  // encoder + type-B embedding -> unified bf16 node table
  enc_gemm<<<(N_TYPE_A + 63) / 64, 256, 0, stream>>>(x_typeA, WmlpBf, b_mlp, xbf);
  embB_copy<<<6250, 256, 0, stream>>>(emb_B, xbf + (size_t)N_TYPE_A * DD);

  // ---- build CSR (both directions), layer-invariant ----
  hipMemsetAsync(cntT, 0, 2 * N_NODES * sizeof(int), stream);
  deg_count<<<(N_EDGES + 255) / 256, 256, 0, stream>>>(edge_src, edge_dst, cntS, cntT);
  scan1<<<2 * SCAN_NBLK, 256, 0, stream>>>(cntT, cntS, rowptrT, rowptrS, bsumsT, bsumsS);
  scan2<<<2, 512, 0, stream>>>(bsumsT, bsumsS);
  scan3<<<2 * SCAN_NBLK, 256, 0, stream>>>(rowptrT, rowptrS, bsumsT, bsumsS,
                                           cntT, cntS, invT, invS);
  fill_kernel<<<(N_EDGES + 255) / 256, 256, 0, stream>>>(
      edge_src, edge_rel, edge_dst, invS, invT, rowptrT, rowptrS, cntT, cntS, payT, payS);

  // ---- two CompGCN layers ----
  agg_kernel<true><<<N_NODES / 4, 256, 0, stream>>>(
      xbf, rel_emb0, rowptrT, payT, rowptrS, payS, nullptr, accObf, accIbf);
  conv_ln<true, true, true><<<(N_NODES + 63) / 64, 256, 0, stream>>>(
      nullptr, accObf, accIbf, xbf, wOutbf0, wInbf0, wLoopbf0, biasAdj0, ln_g0, ln_b0,
      xbf, nullptr);
  agg_kernel<false><<<N_NODES / 4, 256, 0, stream>>>(
      xbf, rel_emb1, rowptrT, payT, rowptrS, payS, accOf, nullptr, accIbf);
  conv_ln<false, false, false><<<(N_NODES + 63) / 64, 256, 0, stream>>>(
      accOf, nullptr, accIbf, xbf, wOutbf1, wInbf1, wLoopbf1, biasAdj1, ln_g1, ln_b1,
      nullptr, out);
}

// Round 9
// 610.087 us; speedup vs baseline: 4.3672x; 1.1228x over previous
//
#include <hip/hip_runtime.h>
#include <hip/hip_bf16.h>

#define N_NODES   100000
#define N_TYPE_A  50000
#define N_EDGES   600000
#define D_IN      256
#define DD        128
#define LN_EPS    1e-5f
#define SCAN_NBLK 391   // ceil(N_NODES/256)

typedef short bf16x8 __attribute__((ext_vector_type(8)));
typedef float f32x4  __attribute__((ext_vector_type(4)));

__device__ __forceinline__ float bf2f(unsigned short u) {
  unsigned v = ((unsigned)u) << 16;
  return __builtin_bit_cast(float, v);
}
__device__ __forceinline__ unsigned short f2bf(float f) {
  unsigned u = __builtin_bit_cast(unsigned, f);
  u += 0x7FFFu + ((u >> 16) & 1u);
  return (unsigned short)(u >> 16);
}

// ------- fused prep: 7 weight f32->bf16 conversions + 2 bias folds + emb_B copy -------
struct PrepArgs {
  const float* src[7];          // W_mlp(32768 elems), wOut0,wIn0,wLoop0,wOut1,wIn1,wLoop1 (16384 ea)
  unsigned short* dst[7];
  const float* bias[2];
  const float* loop[2];
  const float* wloop[2];
  float* biasAdj[2];
  const float* embB;            // 6.4M f32
  unsigned short* embDst;       // xbf + N_TYPE_A*DD
};

__global__ __launch_bounds__(256) void prep_kernel(PrepArgs p) {
  int b = blockIdx.x;
  if (b < 128) {
    int idx = (b * 256 + threadIdx.x) * 4;    // 131072 f32 elems total
    int m, off;
    if (idx < 32768) { m = 0; off = idx; }
    else { int t = idx - 32768; m = 1 + t / 16384; off = t % 16384; }
    const float* s = p.src[m];
    unsigned short* d = p.dst[m];
    float4 v = *(const float4*)(s + off);
    d[off] = f2bf(v.x); d[off+1] = f2bf(v.y); d[off+2] = f2bf(v.z); d[off+3] = f2bf(v.w);
  } else if (b < 130) {
    int L = b - 128;
    if (threadIdx.x < DD) {
      int j = threadIdx.x;
      float s = 0.f;
      for (int k = 0; k < DD; ++k) s += p.loop[L][k] * p.wloop[L][j * DD + k];
      p.biasAdj[L][j] = p.bias[L][j] - s * (1.0f / 3.0f);
    }
  } else {
    size_t i = ((size_t)(b - 130) * 256 + threadIdx.x) * 4;   // 6250 blocks, 6.4M elems
    float4 v = *(const float4*)(p.embB + i);
    unsigned short* o = p.embDst + i;
    o[0] = f2bf(v.x); o[1] = f2bf(v.y); o[2] = f2bf(v.z); o[3] = f2bf(v.w);
  }
}

// ---------------- Encoder: x[0:50000] = x_typeA @ W_mlp.T + b_mlp (bf16 weights) ----------------
__global__ __launch_bounds__(256) void enc_gemm(const float* __restrict__ A,
                                                const unsigned short* __restrict__ Wbf,
                                                const float* __restrict__ bias,
                                                unsigned short* __restrict__ xout) {
  int wave = threadIdx.x >> 6, lane = threadIdx.x & 63;
  int l15 = lane & 15, lhi = lane >> 4;
  int r0 = blockIdx.x * 64 + wave * 16;
  f32x4 acc[8];
#pragma unroll
  for (int i = 0; i < 8; ++i) acc[i] = (f32x4){0.f, 0.f, 0.f, 0.f};
  int rowA = r0 + l15; if (rowA >= N_TYPE_A) rowA = N_TYPE_A - 1;
#pragma unroll
  for (int kk = 0; kk < 8; ++kk) {
    int kbase = kk * 32 + lhi * 8;
    const float* ap = A + (size_t)rowA * D_IN + kbase;
    float4 a0 = *(const float4*)ap; float4 a1 = *(const float4*)(ap + 4);
    bf16x8 af;
    af[0]=f2bf(a0.x); af[1]=f2bf(a0.y); af[2]=f2bf(a0.z); af[3]=f2bf(a0.w);
    af[4]=f2bf(a1.x); af[5]=f2bf(a1.y); af[6]=f2bf(a1.z); af[7]=f2bf(a1.w);
#pragma unroll
    for (int nt = 0; nt < 8; ++nt) {
      bf16x8 bfr = *(const bf16x8*)(Wbf + (size_t)(nt * 16 + l15) * D_IN + kbase);
      acc[nt] = __builtin_amdgcn_mfma_f32_16x16x32_bf16(af, bfr, acc[nt], 0, 0, 0);
    }
  }
#pragma unroll
  for (int nt = 0; nt < 8; ++nt) {
    int col = nt * 16 + l15;
    float bv = bias[col];
#pragma unroll
    for (int r = 0; r < 4; ++r) {
      int row = r0 + lhi * 4 + r;
      if (row < N_TYPE_A) xout[(size_t)row * DD + col] = f2bf(acc[nt][r] + bv);
    }
  }
}

// ---------------- degree count ----------------
__global__ __launch_bounds__(256) void deg_count(const int* __restrict__ es,
                                                 const int* __restrict__ et,
                                                 int* cntS, int* cntT) {
  int e = blockIdx.x * 256 + threadIdx.x;
  if (e < N_EDGES) { atomicAdd(&cntS[es[e]], 1); atomicAdd(&cntT[et[e]], 1); }
}

// ---------------- exclusive scan, both CSRs per launch ----------------
__global__ __launch_bounds__(256) void scan1(const int* __restrict__ cntT,
                                             const int* __restrict__ cntS,
                                             int* __restrict__ rowptrT,
                                             int* __restrict__ rowptrS,
                                             int* __restrict__ bsumsT,
                                             int* __restrict__ bsumsS) {
  __shared__ int tmp[256];
  bool isT = blockIdx.x < SCAN_NBLK;
  int blk = isT ? blockIdx.x : blockIdx.x - SCAN_NBLK;
  const int* cnt = isT ? cntT : cntS;
  int* rowptr = isT ? rowptrT : rowptrS;
  int* bsums  = isT ? bsumsT : bsumsS;
  int gid = blk * 256 + threadIdx.x;
  int v = (gid < N_NODES) ? cnt[gid] : 0;
  tmp[threadIdx.x] = v; __syncthreads();
#pragma unroll
  for (int off = 1; off < 256; off <<= 1) {
    int t = (threadIdx.x >= off) ? tmp[threadIdx.x - off] : 0;
    __syncthreads();
    tmp[threadIdx.x] += t;
    __syncthreads();
  }
  if (gid < N_NODES) rowptr[gid] = tmp[threadIdx.x] - v;
  if (threadIdx.x == 255) bsums[blk] = tmp[255];
}

__global__ __launch_bounds__(512) void scan2(int* __restrict__ bsumsT,
                                             int* __restrict__ bsumsS) {
  __shared__ int tmp[512];
  int* bsums = blockIdx.x ? bsumsS : bsumsT;
  int v = (threadIdx.x < SCAN_NBLK) ? bsums[threadIdx.x] : 0;
  tmp[threadIdx.x] = v; __syncthreads();
#pragma unroll
  for (int off = 1; off < 512; off <<= 1) {
    int t = (threadIdx.x >= off) ? tmp[threadIdx.x - off] : 0;
    __syncthreads();
    tmp[threadIdx.x] += t;
    __syncthreads();
  }
  if (threadIdx.x < SCAN_NBLK) bsums[threadIdx.x] = tmp[threadIdx.x] - v;
}

// ---------------- scan3 + inv-sqrt + cnt rezero (cursor for fill) ----------------
__global__ __launch_bounds__(256) void scan3(int* __restrict__ rowptrT,
                                             int* __restrict__ rowptrS,
                                             const int* __restrict__ bsumsT,
                                             const int* __restrict__ bsumsS,
                                             int* __restrict__ cntT,
                                             int* __restrict__ cntS,
                                             float* __restrict__ invT,
                                             float* __restrict__ invS) {
  bool isT = blockIdx.x < SCAN_NBLK;
  int blk = isT ? blockIdx.x : blockIdx.x - SCAN_NBLK;
  int gid = blk * 256 + threadIdx.x;
  if (gid < N_NODES) {
    if (isT) {
      rowptrT[gid] += bsumsT[blk];
      int c = cntT[gid]; invT[gid] = c > 0 ? rsqrtf((float)c) : 0.f; cntT[gid] = 0;
      if (gid == 0) rowptrT[N_NODES] = N_EDGES;
    } else {
      rowptrS[gid] += bsumsS[blk];
      int c = cntS[gid]; invS[gid] = c > 0 ? rsqrtf((float)c) : 0.f; cntS[gid] = 0;
      if (gid == 0) rowptrS[N_NODES] = N_EDGES;
    }
  }
}

// ---------------- CSR fill: payload = {idx | rel<<17, f32 factor} ----------------
__global__ __launch_bounds__(256) void fill_kernel(const int* __restrict__ es,
                                                   const int* __restrict__ er,
                                                   const int* __restrict__ et,
                                                   const float* __restrict__ invS,
                                                   const float* __restrict__ invT,
                                                   const int* __restrict__ rowptrT,
                                                   const int* __restrict__ rowptrS,
                                                   int* cntT, int* cntS,
                                                   uint2* __restrict__ payT,
                                                   uint2* __restrict__ payS) {
  int e = blockIdx.x * 256 + threadIdx.x;
  if (e >= N_EDGES) return;
  int s = es[e], r = er[e], t = et[e];
  unsigned fb = __builtin_bit_cast(unsigned, invS[s] * invT[t]);
  int pT = rowptrT[t] + atomicAdd(&cntT[t], 1);
  payT[pT] = make_uint2((unsigned)s | ((unsigned)r << 17), fb);
  int pS = rowptrS[s] + atomicAdd(&cntS[s], 1);
  payS[pS] = make_uint2((unsigned)t | ((unsigned)r << 17), fb);
}

// ------- gather aggregation: one wave per node, both directions FUSED for 4-deep MLP -------
#define PROC(P, A0, A1)                                              \
  {                                                                  \
    int _i = (int)(P.x & 131071u); int _r = (int)(P.x >> 17);        \
    float _f = __builtin_bit_cast(float, P.y);                       \
    ushort2 _x = *(const ushort2*)(xd + (size_t)_i * DD);            \
    float2 _re = *(const float2*)(reld + (size_t)_r * DD);           \
    A0 += (bf2f(_x.x) - _re.x) * _f;                                 \
    A1 += (bf2f(_x.y) - _re.y) * _f;                                 \
  }

template<bool OBF>
__global__ __launch_bounds__(256) void agg_kernel(const unsigned short* __restrict__ x,
                                                  const float* __restrict__ rel,
                                                  const int* __restrict__ rowptrT,
                                                  const uint2* __restrict__ payT,
                                                  const int* __restrict__ rowptrS,
                                                  const uint2* __restrict__ payS,
                                                  float* accOf, unsigned short* accObf,
                                                  unsigned short* __restrict__ accIbf) {
  int wave = threadIdx.x >> 6, lane = threadIdx.x & 63;
  int n = __builtin_amdgcn_readfirstlane(blockIdx.x * 4 + wave);
  int d = lane * 2;
  const unsigned short* xd = x + d;
  const float* reld = rel + d;
  float aT0=0.f, aT1=0.f, cT0=0.f, cT1=0.f;
  float aS0=0.f, aS1=0.f, cS0=0.f, cS1=0.f;
  int iT = rowptrT[n], eT = rowptrT[n + 1];
  int iS = rowptrS[n], eS = rowptrS[n + 1];
  // fused main loop: 2 T-edges + 2 S-edges per iteration (wave-uniform bounds -> no divergence)
  while (iT + 1 < eT && iS + 1 < eS) {
    uint2 p0 = payT[iT], p1 = payT[iT + 1];
    uint2 q0 = payS[iS], q1 = payS[iS + 1];
    PROC(p0, aT0, aT1) PROC(p1, cT0, cT1)
    PROC(q0, aS0, aS1) PROC(q1, cS0, cS1)
    iT += 2; iS += 2;
  }
  while (iT + 1 < eT) {
    uint2 p0 = payT[iT], p1 = payT[iT + 1];
    PROC(p0, aT0, aT1) PROC(p1, cT0, cT1)
    iT += 2;
  }
  if (iT < eT) { uint2 p0 = payT[iT]; PROC(p0, aT0, aT1) }
  while (iS + 1 < eS) {
    uint2 q0 = payS[iS], q1 = payS[iS + 1];
    PROC(q0, aS0, aS1) PROC(q1, cS0, cS1)
    iS += 2;
  }
  if (iS < eS) { uint2 q0 = payS[iS]; PROC(q0, aS0, aS1) }

  aT0 += cT0; aT1 += cT1; aS0 += cS0; aS1 += cS1;
  if constexpr (OBF) {
    *(ushort2*)(accObf + (size_t)n * DD + d) = make_ushort2(f2bf(aT0), f2bf(aT1));
  } else {
    accOf[(size_t)n * DD + d]     = aT0;
    accOf[(size_t)n * DD + d + 1] = aT1;
  }
  *(ushort2*)(accIbf + (size_t)n * DD + d) = make_ushort2(f2bf(aS0), f2bf(aS1));
}

// ------- per-layer transform: 3 fused GEMMs (K=384, bf16) + biasAdj + [relu] + LN -------
// NOTE: x / accOf / accObf / outf are NOT __restrict__ — layer0 writes outbf==x (in-place),
// layer1 reads accOf==d_out and writes outf==d_out. Per-wave read-before-write on own rows,
// rows disjoint across waves; legal only without restrict's reordering license.
template<bool RELU, bool OUTBF, bool A0BF>
__global__ __launch_bounds__(256) void conv_ln(const float* accOf,
                                               const unsigned short* accObf,
                                               const unsigned short* accIbf,
                                               const unsigned short* x,
                                               const unsigned short* __restrict__ wOut,
                                               const unsigned short* __restrict__ wIn,
                                               const unsigned short* __restrict__ wLoop,
                                               const float* __restrict__ biasAdj,
                                               const float* __restrict__ g,
                                               const float* __restrict__ bln,
                                               unsigned short* outbf, float* outf) {
  int wave = threadIdx.x >> 6, lane = threadIdx.x & 63;
  int l15 = lane & 15, lhi = lane >> 4;
  int r0 = blockIdx.x * 64 + wave * 16;
  f32x4 acc[8];
#pragma unroll
  for (int i = 0; i < 8; ++i) acc[i] = (f32x4){0.f, 0.f, 0.f, 0.f};
  int rowA = r0 + l15; if (rowA >= N_NODES) rowA = N_NODES - 1;
#pragma unroll
  for (int m = 0; m < 3; ++m) {
    const unsigned short* wmat = (m == 0) ? wOut : ((m == 1) ? wIn : wLoop);
#pragma unroll
    for (int kk = 0; kk < 4; ++kk) {
      int kbase = kk * 32 + lhi * 8;
      bf16x8 af;
      if (m == 0) {
        if constexpr (A0BF) {
          af = *(const bf16x8*)(accObf + (size_t)rowA * DD + kbase);
        } else {
          const float* ap = accOf + (size_t)rowA * DD + kbase;
          float4 a0 = *(const float4*)ap; float4 a1 = *(const float4*)(ap + 4);
          af[0]=f2bf(a0.x); af[1]=f2bf(a0.y); af[2]=f2bf(a0.z); af[3]=f2bf(a0.w);
          af[4]=f2bf(a1.x); af[5]=f2bf(a1.y); af[6]=f2bf(a1.z); af[7]=f2bf(a1.w);
        }
      } else if (m == 1) {
        af = *(const bf16x8*)(accIbf + (size_t)rowA * DD + kbase);
      } else {
        af = *(const bf16x8*)(x + (size_t)rowA * DD + kbase);   // loop_rel folded into biasAdj
      }
#pragma unroll
      for (int nt = 0; nt < 8; ++nt) {
        bf16x8 bfr = *(const bf16x8*)(wmat + (size_t)(nt * 16 + l15) * DD + kbase);
        acc[nt] = __builtin_amdgcn_mfma_f32_16x16x32_bf16(af, bfr, acc[nt], 0, 0, 0);
      }
    }
  }
  float bv[8], gv[8], bb[8];
#pragma unroll
  for (int nt = 0; nt < 8; ++nt) {
    int col = nt * 16 + l15;
    bv[nt] = biasAdj[col]; gv[nt] = g[col]; bb[nt] = bln[col];
  }
  const float third = 1.0f / 3.0f;
  float s0[4] = {0.f, 0.f, 0.f, 0.f}, s1[4] = {0.f, 0.f, 0.f, 0.f};
#pragma unroll
  for (int nt = 0; nt < 8; ++nt)
#pragma unroll
    for (int r = 0; r < 4; ++r) {
      float v = acc[nt][r] * third + bv[nt];
      if (RELU) v = fmaxf(v, 0.f);
      acc[nt][r] = v;
      s0[r] += v; s1[r] += v * v;
    }
#pragma unroll
  for (int off = 1; off < 16; off <<= 1)
#pragma unroll
    for (int r = 0; r < 4; ++r) {
      s0[r] += __shfl_xor(s0[r], off);
      s1[r] += __shfl_xor(s1[r], off);
    }
  float mu[4], rstd[4];
#pragma unroll
  for (int r = 0; r < 4; ++r) {
    mu[r] = s0[r] * (1.f / 128.f);
    float var = s1[r] * (1.f / 128.f) - mu[r] * mu[r];
    rstd[r] = rsqrtf(var + LN_EPS);
  }
#pragma unroll
  for (int nt = 0; nt < 8; ++nt) {
    int col = nt * 16 + l15;
#pragma unroll
    for (int r = 0; r < 4; ++r) {
      int row = r0 + lhi * 4 + r;
      if (row < N_NODES) {
        float y = (acc[nt][r] - mu[r]) * rstd[r] * gv[nt] + bb[nt];
        if (OUTBF) outbf[(size_t)row * DD + col] = f2bf(y);
        else       outf[(size_t)row * DD + col]  = y;
      }
    }
  }
}

extern "C" void kernel_launch(void* const* d_in, const int* in_sizes, int n_in,
                              void* d_out, int out_size, void* d_ws, size_t ws_size,
                              hipStream_t stream) {
  const float* x_typeA  = (const float*)d_in[0];
  const float* W_mlp    = (const float*)d_in[1];
  const float* b_mlp    = (const float*)d_in[2];
  const float* emb_B    = (const float*)d_in[3];
  const float* rel_emb0 = (const float*)d_in[4];
  const float* loop_rel0= (const float*)d_in[5];
  const float* w_loop0  = (const float*)d_in[6];
  const float* w_in0    = (const float*)d_in[7];
  const float* w_out0   = (const float*)d_in[8];
  const float* bias0    = (const float*)d_in[9];
  const float* ln_g0    = (const float*)d_in[10];
  const float* ln_b0    = (const float*)d_in[11];
  const float* rel_emb1 = (const float*)d_in[12];
  const float* loop_rel1= (const float*)d_in[13];
  const float* w_loop1  = (const float*)d_in[14];
  const float* w_in1    = (const float*)d_in[15];
  const float* w_out1   = (const float*)d_in[16];
  const float* bias1    = (const float*)d_in[17];
  const float* ln_g1    = (const float*)d_in[18];
  const float* ln_b1    = (const float*)d_in[19];
  const int* edge_src   = (const int*)d_in[20];
  const int* edge_rel   = (const int*)d_in[21];
  const int* edge_dst   = (const int*)d_in[22];

  // ---- workspace layout, high-water ~63.47 MB (proven-safe) ----
  char* ws = (char*)d_ws;
  unsigned short* xbf    = (unsigned short*)ws;              // [0, 25.6M)
  unsigned short* accIbf = (unsigned short*)(ws + 25600000); // [25.6M, 51.2M)
  float* invS    = (float*)(ws + 51200000);
  float* invT    = (float*)(ws + 51600000);
  int*   cntT    = (int*)(ws + 52000000);                    // cntT+cntS contiguous 800 KB
  int*   cntS    = (int*)(ws + 52400000);
  int*   rowptrT = (int*)(ws + 52800000);
  int*   rowptrS = (int*)(ws + 53200256);
  int*   bsumsT  = (int*)(ws + 53600512);
  int*   bsumsS  = (int*)(ws + 53604608);
  uint2* payT    = (uint2*)(ws + 53608704);                  // 4.8 MB
  uint2* payS    = (uint2*)(ws + 58408704);                  // 4.8 MB
  unsigned short* wbf = (unsigned short*)(ws + 63208704);    // [63208704, 63470848): 262144 B
  float* biasAdj0 = (float*)(ws + 63470848);                 // past wbf end (round-6/7 bug fixed)
  float* biasAdj1 = (float*)(ws + 63471360);                 // end 63471872
  float* accOf   = (float*)d_out;                            // layer1 f32 acc (in-place safe)
  unsigned short* accObf = (unsigned short*)d_out;           // layer0 bf16 acc (conv0 writes xbf only)
  float* out     = (float*)d_out;

  unsigned short* WmlpBf  = wbf;                 // 32768 elems
  unsigned short* wOutbf0 = wbf + 32768;
  unsigned short* wInbf0  = wbf + 49152;
  unsigned short* wLoopbf0= wbf + 65536;
  unsigned short* wOutbf1 = wbf + 81920;
  unsigned short* wInbf1  = wbf + 98304;
  unsigned short* wLoopbf1= wbf + 114688;        // ends at elem 131072 = byte 262144

  // ---- fused prep: weights -> bf16, bias folds, emb_B copy ----
  PrepArgs pa;
  pa.src[0] = W_mlp;  pa.dst[0] = WmlpBf;
  pa.src[1] = w_out0; pa.dst[1] = wOutbf0;
  pa.src[2] = w_in0;  pa.dst[2] = wInbf0;
  pa.src[3] = w_loop0;pa.dst[3] = wLoopbf0;
  pa.src[4] = w_out1; pa.dst[4] = wOutbf1;
  pa.src[5] = w_in1;  pa.dst[5] = wInbf1;
  pa.src[6] = w_loop1;pa.dst[6] = wLoopbf1;
  pa.bias[0] = bias0; pa.bias[1] = bias1;
  pa.loop[0] = loop_rel0; pa.loop[1] = loop_rel1;
  pa.wloop[0] = w_loop0;  pa.wloop[1] = w_loop1;
  pa.biasAdj[0] = biasAdj0; pa.biasAdj[1] = biasAdj1;
  pa.embB = emb_B;
  pa.embDst = xbf + (size_t)N_TYPE_A * DD;
  prep_kernel<<<130 + 6250, 256, 0, stream>>>(pa);

  // encoder -> unified bf16 node table
  enc_gemm<<<(N_TYPE_A + 63) / 64, 256, 0, stream>>>(x_typeA, WmlpBf, b_mlp, xbf);

  // ---- build CSR (both directions), layer-invariant ----
  hipMemsetAsync(cntT, 0, 2 * N_NODES * sizeof(int), stream);
  deg_count<<<(N_EDGES + 255) / 256, 256, 0, stream>>>(edge_src, edge_dst, cntS, cntT);
  scan1<<<2 * SCAN_NBLK, 256, 0, stream>>>(cntT, cntS, rowptrT, rowptrS, bsumsT, bsumsS);
  scan2<<<2, 512, 0, stream>>>(bsumsT, bsumsS);
  scan3<<<2 * SCAN_NBLK, 256, 0, stream>>>(rowptrT, rowptrS, bsumsT, bsumsS,
                                           cntT, cntS, invT, invS);
  fill_kernel<<<(N_EDGES + 255) / 256, 256, 0, stream>>>(
      edge_src, edge_rel, edge_dst, invS, invT, rowptrT, rowptrS, cntT, cntS, payT, payS);

  // ---- two CompGCN layers ----
  agg_kernel<true><<<N_NODES / 4, 256, 0, stream>>>(
      xbf, rel_emb0, rowptrT, payT, rowptrS, payS, nullptr, accObf, accIbf);
  conv_ln<true, true, true><<<(N_NODES + 63) / 64, 256, 0, stream>>>(
      nullptr, accObf, accIbf, xbf, wOutbf0, wInbf0, wLoopbf0, biasAdj0, ln_g0, ln_b0,
      xbf, nullptr);
  agg_kernel<false><<<N_NODES / 4, 256, 0, stream>>>(
      xbf, rel_emb1, rowptrT, payT, rowptrS, payS, accOf, nullptr, accIbf);
  conv_ln<false, false, false><<<(N_NODES + 63) / 64, 256, 0, stream>>>(
      accOf, nullptr, accIbf, xbf, wOutbf1, wInbf1, wLoopbf1, biasAdj1, ln_g1, ln_b1,
      nullptr, out);
}